// Round 1
// baseline (987.878 us; speedup 1.0000x reference)
//
#include <hip/hip_runtime.h>

#define BB 512
#define TT 1024
#define ZZ 8
#define NS 5
#define NINF -10000000000.0f

__device__ __forceinline__ float shflx(float v, int m) { return __shfl_xor(v, m, 64); }

// ---------------- forward scan: one wave per batch ----------------
// lane l = (i = l>>3 [row z], j = l&7 [col z']); prev held in j-form (lane holds prev[l&7])
__global__ __launch_bounds__(64) void fwd_kernel(
    const int* __restrict__ s, const int* __restrict__ x, const float* __restrict__ mask,
    const float* __restrict__ pi, const float* __restrict__ P, const float* __restrict__ K,
    float* __restrict__ alpha, float* __restrict__ loglik)
{
    const int b = blockIdx.x;
    const int l = threadIdx.x;
    const int i = l >> 3, j = l & 7;
    const float k0 = K[l], k1 = K[64 + l], k2 = K[128 + l], k3 = K[192 + l], k4 = K[256 + l];
    const float lpA = __logf(P[i * 2 + 0]);   // logP[z=i][x=0]
    const float lpB = __logf(P[i * 2 + 1]);
    float pv = __logf(pi[j]);                 // prev[j]
    const int base = b * TT;
    const int tr = (j << 3) | i;              // transpose permutation (involution)
    int sC = 0, xC = 0; float mC = 0.f;
    for (int t = 0; t < TT; ++t) {
        const int c = t & 63;
        if (c == 0) {
            sC = s[base + t + l];
            xC = x[base + t + l];
            mC = mask[base + t + l];
        }
        const int   sv = __shfl(sC, c, 64);
        const int   xv = __shfl(xC, c, 64);
        const float mv = __shfl(mC, c, 64);
        // global max over prev (stability)
        float mm = pv;
        mm = fmaxf(mm, shflx(mm, 1)); mm = fmaxf(mm, shflx(mm, 2)); mm = fmaxf(mm, shflx(mm, 4));
        const float p = __expf(pv - mm);                 // p[j]
        const float Kv = (sv == 0) ? k0 : (sv == 1) ? k1 : (sv == 2) ? k2 : (sv == 3) ? k3 : k4;
        float pp = p * Kv;                               // p[j] * K[i,j]
        pp += shflx(pp, 1); pp += shflx(pp, 2); pp += shflx(pp, 4);   // sum over j -> rowsum[i]
        const float val = mm + __logf(pp) + (xv ? lpB : lpA);         // val[i]
        const float valJ = __shfl(val, tr, 64);          // val[j]
        pv = (mv != 0.0f) ? valJ : pv;                   // masked step
        if (l < 8) alpha[(base + t) * 8 + l] = pv;
    }
    // loglik = LSE over final alpha
    float mm = pv;
    mm = fmaxf(mm, shflx(mm, 1)); mm = fmaxf(mm, shflx(mm, 2)); mm = fmaxf(mm, shflx(mm, 4));
    float e = __expf(pv - mm);
    e += shflx(e, 1); e += shflx(e, 2); e += shflx(e, 4);
    if (l == 0) loglik[b] = mm + __logf(e);
}

// ---------------- backward scan: one wave per batch ----------------
// bn held in i-form; result bt in j-form; transpose each step
__global__ __launch_bounds__(64) void bwd_kernel(
    const int* __restrict__ s, const int* __restrict__ x, const float* __restrict__ mask,
    const float* __restrict__ P, const float* __restrict__ K,
    const float* __restrict__ loglik, float* __restrict__ beta)
{
    const int b = blockIdx.x;
    const int l = threadIdx.x;
    const int i = l >> 3, j = l & 7;
    const float k0 = K[l], k1 = K[64 + l], k2 = K[128 + l], k3 = K[192 + l], k4 = K[256 + l];
    const float lpA = __logf(P[i * 2 + 0]);   // logP[z=i][x]
    const float lpB = __logf(P[i * 2 + 1]);
    const float ll = loglik[b];
    const int base = b * TT;
    const int tr = (j << 3) | i;
    int   sn = s[base + TT - 1];              // carried transition index (masked-carry semantics)
    int   xn = x[base + TT - 1];              // carried emission index
    float prevM = mask[base + TT - 1];
    float bnI = 0.f, bnJ = 0.f;               // raw beta[t+1] in both forms
    if (l < 8) beta[(base + TT - 1) * 8 + l] = -ll;
    int sC = 0, xC = 0; float mC = 0.f;
    for (int t = TT - 2; t >= 0; --t) {
        const int c = t & 63;
        if (c == 63 || t == TT - 2) {
            const int cb = base + (t & ~63);
            sC = s[cb + l]; xC = x[cb + l]; mC = mask[cb + l];
        }
        const int   sv = __shfl(sC, c, 64);
        const int   xv = __shfl(xC, c, 64);
        const float m0 = __shfl(mC, c, 64);
        const float m1 = prevM;
        const float u = (xn ? lpB : lpA) + bnI;          // u[i] = lPn[i] + bn[i]
        float mm = u;
        mm = fmaxf(mm, shflx(mm, 8)); mm = fmaxf(mm, shflx(mm, 16)); mm = fmaxf(mm, shflx(mm, 32));
        const float w = __expf(u - mm);
        const float Kv = (sn == 0) ? k0 : (sn == 1) ? k1 : (sn == 2) ? k2 : (sn == 3) ? k3 : k4;
        float pp = w * Kv;                               // w[i] * K[i,j]
        pp += shflx(pp, 8); pp += shflx(pp, 16); pp += shflx(pp, 32); // sum over i -> colsum[j]
        const float btv = mm + __logf(pp);               // bt[j]
        const float btJ = (m1 != 0.0f) ? btv : bnJ;
        if (l < 8) beta[(base + t) * 8 + l] = btJ - ll;  // store normalized
        bnJ = btJ;
        bnI = __shfl(btJ, tr, 64);
        if (m0 != 0.0f) { sn = sv; xn = xv; }
        prevM = m0;
    }
}

// ---------------- gamma + xi: one wave per (b,t) ----------------
__global__ __launch_bounds__(256) void post_kernel(
    const int* __restrict__ s, const int* __restrict__ x, const float* __restrict__ mask,
    const float* __restrict__ P, const float* __restrict__ K,
    const float* __restrict__ alpha, const float* __restrict__ beta,
    float* __restrict__ gamma, float* __restrict__ xi)
{
    __shared__ float Klog[NS * 64];
    const int tid = threadIdx.x;
    for (int q = tid; q < NS * 64; q += 256) Klog[q] = __logf(K[q]);
    __syncthreads();
    const int w = blockIdx.x * 4 + (tid >> 6);
    const int l = tid & 63;
    const int b = w >> 10;          // T = 1024
    const int t = w & (TT - 1);
    const int i = l >> 3, j = l & 7;
    const int bt8 = (b * TT + t) * 8;
    const float aJ = alpha[bt8 + j];
    const float bJ0 = beta[bt8 + j];
    const float m0 = mask[b * TT + t];
    // gamma: normalize alpha+beta over z
    const float gv = aJ + bJ0;
    float mg = gv;
    mg = fmaxf(mg, shflx(mg, 1)); mg = fmaxf(mg, shflx(mg, 2)); mg = fmaxf(mg, shflx(mg, 4));
    float eg = __expf(gv - mg);
    eg += shflx(eg, 1); eg += shflx(eg, 2); eg += shflx(eg, 4);
    const float g = (m0 != 0.0f) ? (gv - (mg + __logf(eg))) : NINF;
    if (l < 8) gamma[bt8 + l] = g;
    if (t < TT - 1) {
        const float m1 = mask[b * TT + t + 1];
        const int   sv = s[b * TT + t];
        const int   xv = x[b * TT + t + 1];
        const float aI = __shfl(aJ, (j << 3) | i, 64);   // alpha[i]
        const float bJ1 = beta[bt8 + 8 + j];             // beta[t+1][j] (normalization cancels)
        const float lpx = xv ? __logf(P[j * 2 + 1]) : __logf(P[j * 2 + 0]); // logP[z=j][x_{t+1}]
        float v = Klog[sv * 64 + l] + aI + bJ1 + lpx;
        float mv = v;
        mv = fmaxf(mv, shflx(mv, 1));  mv = fmaxf(mv, shflx(mv, 2));  mv = fmaxf(mv, shflx(mv, 4));
        mv = fmaxf(mv, shflx(mv, 8));  mv = fmaxf(mv, shflx(mv, 16)); mv = fmaxf(mv, shflx(mv, 32));
        float ev = __expf(v - mv);
        ev += shflx(ev, 1);  ev += shflx(ev, 2);  ev += shflx(ev, 4);
        ev += shflx(ev, 8);  ev += shflx(ev, 16); ev += shflx(ev, 32);
        const float xo = (m1 != 0.0f) ? (v - (mv + __logf(ev))) : NINF;
        xi[(size_t)(b * (TT - 1) + t) * 64 + l] = xo;
    }
}

extern "C" void kernel_launch(void* const* d_in, const int* in_sizes, int n_in,
                              void* d_out, int out_size, void* d_ws, size_t ws_size,
                              hipStream_t stream) {
    const int*   s    = (const int*)d_in[0];
    const int*   x    = (const int*)d_in[1];
    const float* mask = (const float*)d_in[2];
    const float* pi   = (const float*)d_in[3];
    const float* P    = (const float*)d_in[4];
    const float* K    = (const float*)d_in[5];

    float* out    = (float*)d_out;
    float* gamma  = out;                                  // (B,T,Z)
    float* xi     = gamma + (size_t)BB * TT * ZZ;         // (B,T-1,Z,Z)
    float* alpha  = xi + (size_t)BB * (TT - 1) * ZZ * ZZ; // (B,T,Z)
    float* beta   = alpha + (size_t)BB * TT * ZZ;         // (B,T,Z)
    float* loglik = beta + (size_t)BB * TT * ZZ;          // (B,)

    fwd_kernel<<<BB, 64, 0, stream>>>(s, x, mask, pi, P, K, alpha, loglik);
    bwd_kernel<<<BB, 64, 0, stream>>>(s, x, mask, P, K, loglik, beta);
    post_kernel<<<BB * TT / 4, 256, 0, stream>>>(s, x, mask, P, K, alpha, beta, gamma, xi);
}

// Round 2
// 959.259 us; speedup vs baseline: 1.0298x; 1.0298x over previous
//
#include <hip/hip_runtime.h>

#define BB 512
#define TT 1024
#define NINF -10000000000.0f
#define LOG8 2.0794415416798357f

// DPP ctrls: quad_perm xor1=0xB1, xor2=0x4E; row_half_mirror(^7)=0x141; row_ror:8(^8)=0x128
template<int CTRL>
__device__ __forceinline__ float dppf(float x) {
    return __builtin_bit_cast(float, __builtin_amdgcn_update_dpp(
        0, __builtin_bit_cast(int, x), CTRL, 0xF, 0xF, true));
}
// gfx950 permlane swaps: a.rows[1,3] <-> b.rows[0,2] (16) ; a.hi32 <-> b.lo32 (32)
__device__ __forceinline__ void plswap16(float &a, float &b) {
    asm volatile("s_nop 1\n\tv_permlane16_swap_b32 %0, %1" : "+v"(a), "+v"(b));
}
__device__ __forceinline__ void plswap32(float &a, float &b) {
    asm volatile("s_nop 1\n\tv_permlane32_swap_b32 %0, %1" : "+v"(a), "+v"(b));
}

// reduce over lane bits 0-2 (result replicated to all 8 lanes of each group)
__device__ __forceinline__ float rsum_lo(float x) {
    x += dppf<0xB1>(x); x += dppf<0x4E>(x); x += dppf<0x141>(x); return x;
}
__device__ __forceinline__ float rmax_lo(float x) {
    x = fmaxf(x, dppf<0xB1>(x)); x = fmaxf(x, dppf<0x4E>(x)); x = fmaxf(x, dppf<0x141>(x)); return x;
}
// reduce over lane bits 3-5 (replicated to all lanes)
__device__ __forceinline__ float rsum_hi(float x) {
    x += dppf<0x128>(x);
    float a = x, b = x; plswap16(a, b); x = a + b;
    a = x; b = x; plswap32(a, b); x = a + b;
    return x;
}
__device__ __forceinline__ float rmax_hi(float x) {
    x = fmaxf(x, dppf<0x128>(x));
    float a = x, b = x; plswap16(a, b); x = fmaxf(a, b);
    a = x; b = x; plswap32(a, b); x = fmaxf(a, b);
    return x;
}
__device__ __forceinline__ float rsum_all(float x) { return rsum_hi(rsum_lo(x)); }
__device__ __forceinline__ float rmax_all(float x) { return rmax_hi(rmax_lo(x)); }

__device__ __forceinline__ float ksel(const float* k, int sv) {
    float r = k[0];
    r = (sv == 1) ? k[1] : r;
    r = (sv == 2) ? k[2] : r;
    r = (sv == 3) ? k[3] : r;
    r = (sv == 4) ? k[4] : r;
    return r;
}

// ---------------- forward scan (real space, stale rescale, parity layout) ----------------
__global__ __launch_bounds__(64) void fwd_kernel(
    const int* __restrict__ s, const int* __restrict__ x, const float* __restrict__ mask,
    const float* __restrict__ pi, const float* __restrict__ P, const float* __restrict__ K,
    float* __restrict__ alpha, float* __restrict__ loglik)
{
    const int b = blockIdx.x, l = threadIdx.x;
    const int lo = l & 7, hi = l >> 3;
    float kN[5], kT[5];
#pragma unroll
    for (int q = 0; q < 5; ++q) { kN[q] = K[q*64 + l]; kT[q] = K[q*64 + lo*8 + hi]; }
    const float pH0 = P[hi*2+0], pH1 = P[hi*2+1];
    const float pL0 = P[lo*2+0], pL1 = P[lo*2+1];
    float av = pi[lo];            // parity 0: av = a[state=lo], replicated over hi
    float c  = 0.0f;              // log offset: true log-alpha = log(av) + c
    int parity = 0;
    float mst = rmax_all(av);
    float rs  = __builtin_amdgcn_rcpf(mst);
    float lm  = __logf(mst);
    const int base = b * TT;
    int sC = 0, xC = 0; float mC = 0.0f;
    for (int t = 0; t < TT; ++t) {
        const int c63 = t & 63;
        if (c63 == 0) { sC = s[base+t+l]; xC = x[base+t+l]; mC = mask[base+t+l]; }
        const int sv  = __builtin_amdgcn_readlane(sC, c63);
        const int xv  = __builtin_amdgcn_readlane(xC, c63);
        const int mvi = __builtin_amdgcn_readlane(__builtin_bit_cast(int, mC), c63);
        if (mvi != 0) {
            float raw;
            if (parity == 0) {   // prev at lo, out at hi: K[i=hi][j=lo] natural
                raw = rsum_lo(av * ksel(kN, sv)) * (xv ? pH1 : pH0);
                parity = 1;
            } else {             // prev at hi, out at lo: K[i=lo][j=hi] = kT
                raw = rsum_hi(av * ksel(kT, sv)) * (xv ? pL1 : pL0);
                parity = 0;
            }
            av = raw * rs;       // stale rescale (off-path factor)
            c += lm;
            mst = rmax_all(av);  // for NEXT unmasked step (off critical path)
            rs  = __builtin_amdgcn_rcpf(mst);
            lm  = __logf(mst);
        }
        const float la = __logf(av) + c;
        if (parity == 0) { if (hi == 0) alpha[(base+t)*8 + lo] = la; }
        else             { if (lo == 0) alpha[(base+t)*8 + hi] = la; }
    }
    // loglik: each state appears exactly 8x in either layout -> LSE_64 - log(8)
    const float laf = __logf(av) + c;
    const float mm  = rmax_all(laf);
    const float e   = rsum_all(__expf(laf - mm));
    if (l == 0) loglik[b] = mm + __logf(e) - LOG8;
}

// ---------------- backward scan (real space, stale rescale, parity layout) ----------------
__global__ __launch_bounds__(64) void bwd_kernel(
    const int* __restrict__ s, const int* __restrict__ x, const float* __restrict__ mask,
    const float* __restrict__ P, const float* __restrict__ K,
    const float* __restrict__ loglik, float* __restrict__ beta)
{
    const int b = blockIdx.x, l = threadIdx.x;
    const int lo = l & 7, hi = l >> 3;
    float kN[5], kT[5];
#pragma unroll
    for (int q = 0; q < 5; ++q) { kN[q] = K[q*64 + l]; kT[q] = K[q*64 + lo*8 + hi]; }
    const float pH0 = P[hi*2+0], pH1 = P[hi*2+1];
    const float pL0 = P[lo*2+0], pL1 = P[lo*2+1];
    const float ll = loglik[b];
    const int base = b * TT;
    int sn = s[base+TT-1], xn = x[base+TT-1];           // carried indices (masked-carry)
    int m1i = __builtin_bit_cast(int, mask[base+TT-1]); // mask[t+1] flag
    float bv = 1.0f, c = 0.0f;    // true log-beta = log(bv) + c
    int parity = 0;               // bv = b[state=lo] (uniform 1.0 valid in any layout)
    float mst = 1.0f, rs = 1.0f, lm = 0.0f;
    if (l < 8) beta[(base+TT-1)*8 + l] = -ll;
    int sC = 0, xC = 0; float mC = 0.0f;
    for (int t = TT-2; t >= 0; --t) {
        const int c63 = t & 63;
        if (c63 == 63 || t == TT-2) {
            const int cb = base + (t & ~63);
            sC = s[cb+l]; xC = x[cb+l]; mC = mask[cb+l];
        }
        const int sv  = __builtin_amdgcn_readlane(sC, c63);
        const int xv  = __builtin_amdgcn_readlane(xC, c63);
        const int mvi = __builtin_amdgcn_readlane(__builtin_bit_cast(int, mC), c63);
        if (m1i != 0) {            // bt[j] = sum_i Pn[i]*bn[i]*K[sn][i][j]
            float raw;
            if (parity == 0) {     // prev i at lo -> need K[i=lo][j=hi] = kT, out at hi
                raw = rsum_lo(bv * (xn ? pL1 : pL0) * ksel(kT, sn));
                parity = 1;
            } else {               // prev i at hi -> K natural, out at lo
                raw = rsum_hi(bv * (xn ? pH1 : pH0) * ksel(kN, sn));
                parity = 0;
            }
            bv = raw * rs;
            c += lm;
            mst = rmax_all(bv);
            rs  = __builtin_amdgcn_rcpf(mst);
            lm  = __logf(mst);
        }
        const float lb = __logf(bv) + c - ll;
        if (parity == 0) { if (hi == 0) beta[(base+t)*8 + lo] = lb; }
        else             { if (lo == 0) beta[(base+t)*8 + hi] = lb; }
        if (mvi != 0) { sn = sv; xn = xv; }
        m1i = mvi;
    }
}

// ---------------- gamma + xi: one wave per (b,t), all-VALU reductions ----------------
__global__ __launch_bounds__(256) void post_kernel(
    const int* __restrict__ s, const int* __restrict__ x, const float* __restrict__ mask,
    const float* __restrict__ P, const float* __restrict__ K,
    const float* __restrict__ alpha, const float* __restrict__ beta,
    float* __restrict__ gamma, float* __restrict__ xi)
{
    const int tid = threadIdx.x;
    const int w = blockIdx.x * 4 + (tid >> 6);
    const int l = tid & 63;
    const int b = w >> 10;          // T = 1024
    const int t = w & (TT - 1);
    const int lo = l & 7, hi = l >> 3;
    const int bt = b * TT + t;
    const int bt8 = bt * 8;
    const float aLo = alpha[bt8 + lo];
    const float bLo = beta[bt8 + lo];
    const float m0 = mask[bt];
    const float gv = aLo + bLo;
    const float mg = rmax_lo(gv);
    const float eg = rsum_lo(__expf(gv - mg));
    const float g = (m0 != 0.0f) ? (gv - (mg + __logf(eg))) : NINF;
    if (hi == 0) gamma[bt8 + lo] = g;
    if (t < TT - 1) {
        const float m1 = mask[bt + 1];
        const int sv = s[bt];
        const int xv = x[bt + 1];
        const float aHi = alpha[bt8 + hi];        // log_alpha[t][i], i=hi
        const float bN  = beta[bt8 + 8 + lo];     // log_beta[t+1][j], j=lo (norm cancels)
        const float lpx = __logf(P[lo*2 + xv]);   // logP[z=j][x_{t+1}]
        const float lk  = __logf(K[sv*64 + l]);   // logK[s_t][i][j]
        float v = lk + aHi + bN + lpx;
        const float mv = rmax_all(v);
        const float ev = rsum_all(__expf(v - mv));
        const float xo = (m1 != 0.0f) ? (v - (mv + __logf(ev))) : NINF;
        xi[(size_t)(b*(TT-1) + t)*64 + l] = xo;
    }
}

extern "C" void kernel_launch(void* const* d_in, const int* in_sizes, int n_in,
                              void* d_out, int out_size, void* d_ws, size_t ws_size,
                              hipStream_t stream) {
    const int*   s    = (const int*)d_in[0];
    const int*   x    = (const int*)d_in[1];
    const float* mask = (const float*)d_in[2];
    const float* pi   = (const float*)d_in[3];
    const float* P    = (const float*)d_in[4];
    const float* K    = (const float*)d_in[5];

    float* out    = (float*)d_out;
    float* gamma  = out;                                  // (B,T,Z)
    float* xi     = gamma + (size_t)BB * TT * 8;          // (B,T-1,Z,Z)
    float* alpha  = xi + (size_t)BB * (TT - 1) * 64;      // (B,T,Z)
    float* beta   = alpha + (size_t)BB * TT * 8;          // (B,T,Z)
    float* loglik = beta + (size_t)BB * TT * 8;           // (B,)

    fwd_kernel<<<BB, 64, 0, stream>>>(s, x, mask, pi, P, K, alpha, loglik);
    bwd_kernel<<<BB, 64, 0, stream>>>(s, x, mask, P, K, loglik, beta);
    post_kernel<<<BB * TT / 4, 256, 0, stream>>>(s, x, mask, P, K, alpha, beta, gamma, xi);
}

// Round 3
// 896.020 us; speedup vs baseline: 1.1025x; 1.0706x over previous
//
#include <hip/hip_runtime.h>

#define BB 512
#define TT 1024
#define NINF -10000000000.0f
#define LOG8 2.0794415416798357f

// DPP ctrls: quad_perm xor1=0xB1, xor2=0x4E; row_half_mirror(^7)=0x141; row_ror:8(^8)=0x128
template<int CTRL>
__device__ __forceinline__ float dppf(float x) {
    return __builtin_bit_cast(float, __builtin_amdgcn_update_dpp(
        0, __builtin_bit_cast(int, x), CTRL, 0xF, 0xF, true));
}
// gfx950 permlane swaps: a.rows[1,3] <-> b.rows[0,2] (16) ; a.hi32 <-> b.lo32 (32)
__device__ __forceinline__ void plswap16(float &a, float &b) {
    asm volatile("s_nop 1\n\tv_permlane16_swap_b32 %0, %1" : "+v"(a), "+v"(b));
}
__device__ __forceinline__ void plswap32(float &a, float &b) {
    asm volatile("s_nop 1\n\tv_permlane32_swap_b32 %0, %1" : "+v"(a), "+v"(b));
}

// reduce over lane bits 0-2 (result replicated to all 8 lanes of each group)
__device__ __forceinline__ float rsum_lo(float x) {
    x += dppf<0xB1>(x); x += dppf<0x4E>(x); x += dppf<0x141>(x); return x;
}
__device__ __forceinline__ float rmax_lo(float x) {
    x = fmaxf(x, dppf<0xB1>(x)); x = fmaxf(x, dppf<0x4E>(x)); x = fmaxf(x, dppf<0x141>(x)); return x;
}
// reduce over lane bits 3-5 (replicated to all lanes)
__device__ __forceinline__ float rsum_hi(float x) {
    x += dppf<0x128>(x);
    float a = x, b = x; plswap16(a, b); x = a + b;
    a = x; b = x; plswap32(a, b); x = a + b;
    return x;
}
__device__ __forceinline__ float rmax_hi(float x) {
    x = fmaxf(x, dppf<0x128>(x));
    float a = x, b = x; plswap16(a, b); x = fmaxf(a, b);
    a = x; b = x; plswap32(a, b); x = fmaxf(a, b);
    return x;
}
__device__ __forceinline__ float rsum_all(float x) { return rsum_hi(rsum_lo(x)); }
__device__ __forceinline__ float rmax_all(float x) { return rmax_hi(rmax_lo(x)); }

// pure-register 5-way select on wave-uniform sv (NO arrays -> no alloca -> no LDS/scratch)
__device__ __forceinline__ float ksel5(float k0, float k1, float k2, float k3, float k4, int sv) {
    float r = k0;
    r = (sv == 1) ? k1 : r;
    r = (sv == 2) ? k2 : r;
    r = (sv == 3) ? k3 : r;
    r = (sv == 4) ? k4 : r;
    return r;
}

// ---------------- forward scan (real space, stale rescale, parity layout) ----------------
__global__ __launch_bounds__(64) void fwd_kernel(
    const int* __restrict__ s, const int* __restrict__ x, const float* __restrict__ mask,
    const float* __restrict__ pi, const float* __restrict__ P, const float* __restrict__ K,
    float* __restrict__ alpha, float* __restrict__ loglik)
{
    const int b = blockIdx.x, l = threadIdx.x;
    const int lo = l & 7, hi = l >> 3;
    // K natural [i=hi][j=lo] and transposed [i=lo][j=hi], in named registers
    const float kN0 = K[0*64 + l],          kN1 = K[1*64 + l],          kN2 = K[2*64 + l],
                kN3 = K[3*64 + l],          kN4 = K[4*64 + l];
    const float kT0 = K[0*64 + lo*8 + hi],  kT1 = K[1*64 + lo*8 + hi],  kT2 = K[2*64 + lo*8 + hi],
                kT3 = K[3*64 + lo*8 + hi],  kT4 = K[4*64 + lo*8 + hi];
    const float pH0 = P[hi*2+0], pH1 = P[hi*2+1];
    const float pL0 = P[lo*2+0], pL1 = P[lo*2+1];
    float av = pi[lo];            // parity 0: av = a[state=lo], replicated over hi
    float c  = 0.0f;              // log offset: true log-alpha = log(av) + c
    int parity = 0;
    float mst = rmax_all(av);
    float rs  = __builtin_amdgcn_rcpf(mst);
    float lm  = __logf(mst);
    const int base = b * TT;
    int sC = 0, xC = 0; float mC = 0.0f;
    for (int t = 0; t < TT; ++t) {
        const int c63 = t & 63;
        if (c63 == 0) { sC = s[base+t+l]; xC = x[base+t+l]; mC = mask[base+t+l]; }
        const int sv  = __builtin_amdgcn_readlane(sC, c63);
        const int xv  = __builtin_amdgcn_readlane(xC, c63);
        const int mvi = __builtin_amdgcn_readlane(__builtin_bit_cast(int, mC), c63);
        if (mvi != 0) {
            float raw;
            if (parity == 0) {   // prev at lo, out at hi: K[i=hi][j=lo] natural
                raw = rsum_lo(av * ksel5(kN0,kN1,kN2,kN3,kN4, sv)) * (xv ? pH1 : pH0);
                parity = 1;
            } else {             // prev at hi, out at lo: K[i=lo][j=hi] = kT
                raw = rsum_hi(av * ksel5(kT0,kT1,kT2,kT3,kT4, sv)) * (xv ? pL1 : pL0);
                parity = 0;
            }
            av = raw * rs;       // rescale by stale max (parallel path from av(t-1))
            c += lm;
            mst = rmax_all(av);  // for NEXT unmasked step
            rs  = __builtin_amdgcn_rcpf(mst);
            lm  = __logf(mst);
        }
        const float la = __logf(av) + c;
        if (parity == 0) { if (hi == 0) alpha[(base+t)*8 + lo] = la; }
        else             { if (lo == 0) alpha[(base+t)*8 + hi] = la; }
    }
    // loglik: each state appears exactly 8x in either layout -> LSE_64 - log(8)
    const float laf = __logf(av) + c;
    const float mm  = rmax_all(laf);
    const float e   = rsum_all(__expf(laf - mm));
    if (l == 0) loglik[b] = mm + __logf(e) - LOG8;
}

// ---------------- backward scan (real space, stale rescale, parity layout) ----------------
__global__ __launch_bounds__(64) void bwd_kernel(
    const int* __restrict__ s, const int* __restrict__ x, const float* __restrict__ mask,
    const float* __restrict__ P, const float* __restrict__ K,
    const float* __restrict__ loglik, float* __restrict__ beta)
{
    const int b = blockIdx.x, l = threadIdx.x;
    const int lo = l & 7, hi = l >> 3;
    const float kN0 = K[0*64 + l],          kN1 = K[1*64 + l],          kN2 = K[2*64 + l],
                kN3 = K[3*64 + l],          kN4 = K[4*64 + l];
    const float kT0 = K[0*64 + lo*8 + hi],  kT1 = K[1*64 + lo*8 + hi],  kT2 = K[2*64 + lo*8 + hi],
                kT3 = K[3*64 + lo*8 + hi],  kT4 = K[4*64 + lo*8 + hi];
    const float pH0 = P[hi*2+0], pH1 = P[hi*2+1];
    const float pL0 = P[lo*2+0], pL1 = P[lo*2+1];
    const float ll = loglik[b];
    const int base = b * TT;
    int sn = s[base+TT-1], xn = x[base+TT-1];           // carried indices (masked-carry)
    int m1i = __builtin_bit_cast(int, mask[base+TT-1]); // mask[t+1] flag
    float bv = 1.0f, c = 0.0f;    // true log-beta = log(bv) + c
    int parity = 0;               // bv uniform 1.0 valid in any layout
    float mst = 1.0f, rs = 1.0f, lm = 0.0f;
    if (l < 8) beta[(base+TT-1)*8 + l] = -ll;
    int sC = 0, xC = 0; float mC = 0.0f;
    for (int t = TT-2; t >= 0; --t) {
        const int c63 = t & 63;
        if (c63 == 63 || t == TT-2) {
            const int cb = base + (t & ~63);
            sC = s[cb+l]; xC = x[cb+l]; mC = mask[cb+l];
        }
        const int sv  = __builtin_amdgcn_readlane(sC, c63);
        const int xv  = __builtin_amdgcn_readlane(xC, c63);
        const int mvi = __builtin_amdgcn_readlane(__builtin_bit_cast(int, mC), c63);
        if (m1i != 0) {            // bt[j] = sum_i Pn[i]*bn[i]*K[sn][i][j]
            float raw;
            if (parity == 0) {     // prev i at lo -> K[i=lo][j=hi] = kT, out at hi
                raw = rsum_lo(bv * (xn ? pL1 : pL0) * ksel5(kT0,kT1,kT2,kT3,kT4, sn));
                parity = 1;
            } else {               // prev i at hi -> K natural, out at lo
                raw = rsum_hi(bv * (xn ? pH1 : pH0) * ksel5(kN0,kN1,kN2,kN3,kN4, sn));
                parity = 0;
            }
            bv = raw * rs;
            c += lm;
            mst = rmax_all(bv);
            rs  = __builtin_amdgcn_rcpf(mst);
            lm  = __logf(mst);
        }
        const float lb = __logf(bv) + c - ll;
        if (parity == 0) { if (hi == 0) beta[(base+t)*8 + lo] = lb; }
        else             { if (lo == 0) beta[(base+t)*8 + hi] = lb; }
        if (mvi != 0) { sn = sv; xn = xv; }
        m1i = mvi;
    }
}

// ---------------- gamma + xi: one wave per (b,t), all-VALU reductions ----------------
__global__ __launch_bounds__(256) void post_kernel(
    const int* __restrict__ s, const int* __restrict__ x, const float* __restrict__ mask,
    const float* __restrict__ P, const float* __restrict__ K,
    const float* __restrict__ alpha, const float* __restrict__ beta,
    float* __restrict__ gamma, float* __restrict__ xi)
{
    const int tid = threadIdx.x;
    const int w = blockIdx.x * 4 + (tid >> 6);
    const int l = tid & 63;
    const int b = w >> 10;          // T = 1024
    const int t = w & (TT - 1);
    const int lo = l & 7, hi = l >> 3;
    const int bt = b * TT + t;
    const int bt8 = bt * 8;
    const float aLo = alpha[bt8 + lo];
    const float bLo = beta[bt8 + lo];
    const float m0 = mask[bt];
    const float gv = aLo + bLo;
    const float mg = rmax_lo(gv);
    const float eg = rsum_lo(__expf(gv - mg));
    const float g = (m0 != 0.0f) ? (gv - (mg + __logf(eg))) : NINF;
    if (hi == 0) gamma[bt8 + lo] = g;
    if (t < TT - 1) {
        const float m1 = mask[bt + 1];
        const int sv = s[bt];
        const int xv = x[bt + 1];
        const float aHi = alpha[bt8 + hi];        // log_alpha[t][i], i=hi
        const float bN  = beta[bt8 + 8 + lo];     // log_beta[t+1][j], j=lo (norm cancels)
        const float lpx = __logf(P[lo*2 + xv]);   // logP[z=j][x_{t+1}]
        const float lk  = __logf(K[sv*64 + l]);   // logK[s_t][i][j]
        float v = lk + aHi + bN + lpx;
        const float mv = rmax_all(v);
        const float ev = rsum_all(__expf(v - mv));
        const float xo = (m1 != 0.0f) ? (v - (mv + __logf(ev))) : NINF;
        xi[(size_t)(b*(TT-1) + t)*64 + l] = xo;
    }
}

extern "C" void kernel_launch(void* const* d_in, const int* in_sizes, int n_in,
                              void* d_out, int out_size, void* d_ws, size_t ws_size,
                              hipStream_t stream) {
    const int*   s    = (const int*)d_in[0];
    const int*   x    = (const int*)d_in[1];
    const float* mask = (const float*)d_in[2];
    const float* pi   = (const float*)d_in[3];
    const float* P    = (const float*)d_in[4];
    const float* K    = (const float*)d_in[5];

    float* out    = (float*)d_out;
    float* gamma  = out;                                  // (B,T,Z)
    float* xi     = gamma + (size_t)BB * TT * 8;          // (B,T-1,Z,Z)
    float* alpha  = xi + (size_t)BB * (TT - 1) * 64;      // (B,T,Z)
    float* beta   = alpha + (size_t)BB * TT * 8;          // (B,T,Z)
    float* loglik = beta + (size_t)BB * TT * 8;           // (B,)

    fwd_kernel<<<BB, 64, 0, stream>>>(s, x, mask, pi, P, K, alpha, loglik);
    bwd_kernel<<<BB, 64, 0, stream>>>(s, x, mask, P, K, loglik, beta);
    post_kernel<<<BB * TT / 4, 256, 0, stream>>>(s, x, mask, P, K, alpha, beta, gamma, xi);
}

// Round 4
// 615.812 us; speedup vs baseline: 1.6042x; 1.4550x over previous
//
#include <hip/hip_runtime.h>

#define BB 512
#define TT 1024
#define NINF -10000000000.0f
#define LOG8 2.0794415416798357f

// DPP ctrls: quad_perm xor1=0xB1, xor2=0x4E; row_half_mirror(^7)=0x141; row_ror:8(^8)=0x128
template<int CTRL>
__device__ __forceinline__ float dppf(float x) {
    return __builtin_bit_cast(float, __builtin_amdgcn_update_dpp(
        0, __builtin_bit_cast(int, x), CTRL, 0xF, 0xF, true));
}
__device__ __forceinline__ void plswap16(float &a, float &b) {
    asm volatile("s_nop 1\n\tv_permlane16_swap_b32 %0, %1" : "+v"(a), "+v"(b));
}
__device__ __forceinline__ void plswap32(float &a, float &b) {
    asm volatile("s_nop 1\n\tv_permlane32_swap_b32 %0, %1" : "+v"(a), "+v"(b));
}

// reduce over lane bits 0-2 (replicated to the 8 lanes of each group)
__device__ __forceinline__ float rsum_lo(float x) {
    x += dppf<0xB1>(x); x += dppf<0x4E>(x); x += dppf<0x141>(x); return x;
}
__device__ __forceinline__ float rmax_lo(float x) {
    x = fmaxf(x, dppf<0xB1>(x)); x = fmaxf(x, dppf<0x4E>(x)); x = fmaxf(x, dppf<0x141>(x)); return x;
}
// reduce over lane bits 3-5 (replicated)
__device__ __forceinline__ float rsum_hi(float x) {
    x += dppf<0x128>(x);
    float a = x, b = x; plswap16(a, b); x = a + b;
    a = x; b = x; plswap32(a, b); x = a + b;
    return x;
}
__device__ __forceinline__ float rmax_hi(float x) {
    x = fmaxf(x, dppf<0x128>(x));
    float a = x, b = x; plswap16(a, b); x = fmaxf(a, b);
    a = x; b = x; plswap32(a, b); x = fmaxf(a, b);
    return x;
}
__device__ __forceinline__ float rsum_all(float x) { return rsum_hi(rsum_lo(x)); }
__device__ __forceinline__ float rmax_all(float x) { return rmax_hi(rmax_lo(x)); }

// pure-register 5-way select on wave-uniform sv
__device__ __forceinline__ float ksel5(float k0, float k1, float k2, float k3, float k4, int sv) {
    float r = k0;
    r = (sv == 1) ? k1 : r;
    r = (sv == 2) ? k2 : r;
    r = (sv == 3) ? k3 : r;
    r = (sv == 4) ? k4 : r;
    return r;
}

#define ANCHORF(v) asm volatile("" : "+v"(v))
#define ANCHORI(v) asm volatile("" : "+v"(v))

// ---------------- forward scan: no vector loads inside the loop ----------------
__global__ __launch_bounds__(64) void fwd_kernel(
    const int* __restrict__ s, const int* __restrict__ x, const float* __restrict__ mask,
    const float* __restrict__ pi, const float* __restrict__ P, const float* __restrict__ K,
    float* __restrict__ alpha, float* __restrict__ loglik)
{
    const int b = blockIdx.x, l = threadIdx.x;
    const int lo = l & 7, hi = l >> 3;
    float kN0 = K[0*64 + l],         kN1 = K[1*64 + l],         kN2 = K[2*64 + l],
          kN3 = K[3*64 + l],         kN4 = K[4*64 + l];
    float kT0 = K[0*64 + lo*8 + hi], kT1 = K[1*64 + lo*8 + hi], kT2 = K[2*64 + lo*8 + hi],
          kT3 = K[3*64 + lo*8 + hi], kT4 = K[4*64 + lo*8 + hi];
    float pH0 = P[hi*2+0], pH1 = P[hi*2+1];
    float pL0 = P[lo*2+0], pL1 = P[lo*2+1];
    const int base = b * TT;
    // control preload: reg r, lane l  <->  t = l*16 + r
    int sR[16], xR[16]; float mR[16];
#pragma unroll
    for (int r = 0; r < 16; ++r) {
        sR[r] = s[base + l*16 + r];
        xR[r] = x[base + l*16 + r];
        mR[r] = mask[base + l*16 + r];
    }
    float av = pi[lo];            // parity 0: av = a[state=lo], replicated over hi
    __builtin_amdgcn_s_waitcnt(0);   // clear all counters BEFORE the loop
#pragma unroll
    for (int r = 0; r < 16; ++r) { ANCHORI(sR[r]); ANCHORI(xR[r]); ANCHORF(mR[r]); }
    ANCHORF(kN0); ANCHORF(kN1); ANCHORF(kN2); ANCHORF(kN3); ANCHORF(kN4);
    ANCHORF(kT0); ANCHORF(kT1); ANCHORF(kT2); ANCHORF(kT3); ANCHORF(kT4);
    ANCHORF(pH0); ANCHORF(pH1); ANCHORF(pL0); ANCHORF(pL1); ANCHORF(av);

    float c  = 0.0f;              // true log-alpha = log(av) + c
    int parity = 0;
    float mst = rmax_all(av);
    float rs  = __builtin_amdgcn_rcpf(mst);
    float lm  = __logf(mst);
    int bt8 = base * 8;
    for (int tq = 0; tq < 64; ++tq) {
#pragma unroll
        for (int r = 0; r < 16; ++r) {
            const int sv  = __builtin_amdgcn_readlane(sR[r], tq);
            const int xv  = __builtin_amdgcn_readlane(xR[r], tq);
            const int mvi = __builtin_amdgcn_readlane(__builtin_bit_cast(int, mR[r]), tq);
            if (mvi != 0) {
                float raw;
                if (parity == 0) {   // prev at lo, out at hi: K natural [i=hi][j=lo]
                    raw = rsum_lo(av * ksel5(kN0,kN1,kN2,kN3,kN4, sv)) * (xv ? pH1 : pH0);
                    parity = 1;
                } else {             // prev at hi, out at lo: K^T [i=lo][j=hi]
                    raw = rsum_hi(av * ksel5(kT0,kT1,kT2,kT3,kT4, sv)) * (xv ? pL1 : pL0);
                    parity = 0;
                }
                av = raw * rs;       // stale rescale (off the critical join)
                c += lm;
                mst = rmax_all(av);
                rs  = __builtin_amdgcn_rcpf(mst);
                lm  = __logf(mst);
            }
            const float la = __logf(av) + c;
            alpha[bt8 + (parity == 0 ? lo : hi)] = la;   // replicated same-data store
            bt8 += 8;
        }
    }
    const float laf = __logf(av) + c;
    const float mm  = rmax_all(laf);
    const float e   = rsum_all(__expf(laf - mm));
    if (l == 0) loglik[b] = mm + __logf(e) - LOG8;
}

// ---------------- backward scan: no vector loads inside the loop ----------------
__global__ __launch_bounds__(64) void bwd_kernel(
    const int* __restrict__ s, const int* __restrict__ x, const float* __restrict__ mask,
    const float* __restrict__ P, const float* __restrict__ K,
    const float* __restrict__ loglik, float* __restrict__ beta)
{
    const int b = blockIdx.x, l = threadIdx.x;
    const int lo = l & 7, hi = l >> 3;
    float kN0 = K[0*64 + l],         kN1 = K[1*64 + l],         kN2 = K[2*64 + l],
          kN3 = K[3*64 + l],         kN4 = K[4*64 + l];
    float kT0 = K[0*64 + lo*8 + hi], kT1 = K[1*64 + lo*8 + hi], kT2 = K[2*64 + lo*8 + hi],
          kT3 = K[3*64 + lo*8 + hi], kT4 = K[4*64 + lo*8 + hi];
    float pH0 = P[hi*2+0], pH1 = P[hi*2+1];
    float pL0 = P[lo*2+0], pL1 = P[lo*2+1];
    float ll  = loglik[b];
    const int base = b * TT;
    int sR[16], xR[16]; float mR[16];
#pragma unroll
    for (int r = 0; r < 16; ++r) {
        sR[r] = s[base + l*16 + r];
        xR[r] = x[base + l*16 + r];
        mR[r] = mask[base + l*16 + r];
    }
    __builtin_amdgcn_s_waitcnt(0);
#pragma unroll
    for (int r = 0; r < 16; ++r) { ANCHORI(sR[r]); ANCHORI(xR[r]); ANCHORF(mR[r]); }
    ANCHORF(kN0); ANCHORF(kN1); ANCHORF(kN2); ANCHORF(kN3); ANCHORF(kN4);
    ANCHORF(kT0); ANCHORF(kT1); ANCHORF(kT2); ANCHORF(kT3); ANCHORF(kT4);
    ANCHORF(pH0); ANCHORF(pH1); ANCHORF(pL0); ANCHORF(pL1); ANCHORF(ll);

    // init at t = TT-1 (tq=63, r=15) straight from the preloaded registers
    int sn  = __builtin_amdgcn_readlane(sR[15], 63);
    int xn  = __builtin_amdgcn_readlane(xR[15], 63);
    int m1i = __builtin_amdgcn_readlane(__builtin_bit_cast(int, mR[15]), 63);
    float bv = 1.0f, c = 0.0f;    // true log-beta = log(bv) + c
    int parity = 0;
    float mst = 1.0f, rs = 1.0f, lm = 0.0f;
    beta[(base + TT - 1)*8 + lo] = -ll;                  // replicated store
    int bt8 = (base + TT - 2) * 8;
    for (int tq = 63; tq >= 0; --tq) {
#pragma unroll
        for (int r = 15; r >= 0; --r) {
            if (r == 15 && tq == 63) continue;           // t=1023 already handled
            const int sv  = __builtin_amdgcn_readlane(sR[r], tq);
            const int xv  = __builtin_amdgcn_readlane(xR[r], tq);
            const int mvi = __builtin_amdgcn_readlane(__builtin_bit_cast(int, mR[r]), tq);
            if (m1i != 0) {          // bt[j] = sum_i Pn[i]*bn[i]*K[sn][i][j]
                float raw;
                if (parity == 0) {   // prev i at lo -> K^T [i=lo][j=hi], out at hi
                    raw = rsum_lo(bv * (xn ? pL1 : pL0) * ksel5(kT0,kT1,kT2,kT3,kT4, sn));
                    parity = 1;
                } else {             // prev i at hi -> K natural, out at lo
                    raw = rsum_hi(bv * (xn ? pH1 : pH0) * ksel5(kN0,kN1,kN2,kN3,kN4, sn));
                    parity = 0;
                }
                bv = raw * rs;
                c += lm;
                mst = rmax_all(bv);
                rs  = __builtin_amdgcn_rcpf(mst);
                lm  = __logf(mst);
            }
            const float lb = __logf(bv) + c - ll;
            beta[bt8 + (parity == 0 ? lo : hi)] = lb;    // replicated same-data store
            bt8 -= 8;
            if (mvi != 0) { sn = sv; xn = xv; }
            m1i = mvi;
        }
    }
}

// ---------------- gamma + xi: one wave per (b,t), all-VALU reductions ----------------
__global__ __launch_bounds__(256) void post_kernel(
    const int* __restrict__ s, const int* __restrict__ x, const float* __restrict__ mask,
    const float* __restrict__ P, const float* __restrict__ K,
    const float* __restrict__ alpha, const float* __restrict__ beta,
    float* __restrict__ gamma, float* __restrict__ xi)
{
    const int tid = threadIdx.x;
    const int w = blockIdx.x * 4 + (tid >> 6);
    const int l = tid & 63;
    const int b = w >> 10;          // T = 1024
    const int t = w & (TT - 1);
    const int lo = l & 7, hi = l >> 3;
    const int bt = b * TT + t;
    const int bt8 = bt * 8;
    const float aLo = alpha[bt8 + lo];
    const float bLo = beta[bt8 + lo];
    const float m0 = mask[bt];
    const float gv = aLo + bLo;
    const float mg = rmax_lo(gv);
    const float eg = rsum_lo(__expf(gv - mg));
    const float g = (m0 != 0.0f) ? (gv - (mg + __logf(eg))) : NINF;
    if (hi == 0) gamma[bt8 + lo] = g;
    if (t < TT - 1) {
        const float m1 = mask[bt + 1];
        const int sv = s[bt];
        const int xv = x[bt + 1];
        const float aHi = alpha[bt8 + hi];        // log_alpha[t][i], i=hi
        const float bN  = beta[bt8 + 8 + lo];     // log_beta[t+1][j], j=lo (norm cancels)
        const float lpx = __logf(P[lo*2 + xv]);   // logP[z=j][x_{t+1}]
        const float lk  = __logf(K[sv*64 + l]);   // logK[s_t][i][j]
        float v = lk + aHi + bN + lpx;
        const float mv = rmax_all(v);
        const float ev = rsum_all(__expf(v - mv));
        const float xo = (m1 != 0.0f) ? (v - (mv + __logf(ev))) : NINF;
        xi[(size_t)(b*(TT-1) + t)*64 + l] = xo;
    }
}

extern "C" void kernel_launch(void* const* d_in, const int* in_sizes, int n_in,
                              void* d_out, int out_size, void* d_ws, size_t ws_size,
                              hipStream_t stream) {
    const int*   s    = (const int*)d_in[0];
    const int*   x    = (const int*)d_in[1];
    const float* mask = (const float*)d_in[2];
    const float* pi   = (const float*)d_in[3];
    const float* P    = (const float*)d_in[4];
    const float* K    = (const float*)d_in[5];

    float* out    = (float*)d_out;
    float* gamma  = out;                                  // (B,T,Z)
    float* xi     = gamma + (size_t)BB * TT * 8;          // (B,T-1,Z,Z)
    float* alpha  = xi + (size_t)BB * (TT - 1) * 64;      // (B,T,Z)
    float* beta   = alpha + (size_t)BB * TT * 8;          // (B,T,Z)
    float* loglik = beta + (size_t)BB * TT * 8;           // (B,)

    fwd_kernel<<<BB, 64, 0, stream>>>(s, x, mask, pi, P, K, alpha, loglik);
    bwd_kernel<<<BB, 64, 0, stream>>>(s, x, mask, P, K, loglik, beta);
    post_kernel<<<BB * TT / 4, 256, 0, stream>>>(s, x, mask, P, K, alpha, beta, gamma, xi);
}

// Round 5
// 404.435 us; speedup vs baseline: 2.4426x; 1.5226x over previous
//
#include <hip/hip_runtime.h>

#define BB 512
#define TT 1024
#define NINF -10000000000.0f

// DPP ctrls: quad_perm xor1=0xB1, xor2=0x4E; row_half_mirror(^7)=0x141; row_ror:8(^8)=0x128
template<int CTRL>
__device__ __forceinline__ float dppf(float x) {
    return __builtin_bit_cast(float, __builtin_amdgcn_update_dpp(
        0, __builtin_bit_cast(int, x), CTRL, 0xF, 0xF, true));
}
__device__ __forceinline__ void plswap16(float &a, float &b) {
    asm volatile("s_nop 1\n\tv_permlane16_swap_b32 %0, %1" : "+v"(a), "+v"(b));
}
__device__ __forceinline__ void plswap32(float &a, float &b) {
    asm volatile("s_nop 1\n\tv_permlane32_swap_b32 %0, %1" : "+v"(a), "+v"(b));
}

// reduce over lane bits 0-2 (replicated within each 8-lane group)
__device__ __forceinline__ float rsum_lo(float x) {
    x += dppf<0xB1>(x); x += dppf<0x4E>(x); x += dppf<0x141>(x); return x;
}
__device__ __forceinline__ float rmax_lo(float x) {
    x = fmaxf(x, dppf<0xB1>(x)); x = fmaxf(x, dppf<0x4E>(x)); x = fmaxf(x, dppf<0x141>(x)); return x;
}
// reduce over lane bits 3-5 (replicated)
__device__ __forceinline__ float rsum_hi(float x) {
    x += dppf<0x128>(x);
    float a = x, b = x; plswap16(a, b); x = a + b;
    a = x; b = x; plswap32(a, b); x = a + b;
    return x;
}
__device__ __forceinline__ float rmax_hi(float x) {
    x = fmaxf(x, dppf<0x128>(x));
    float a = x, b = x; plswap16(a, b); x = fmaxf(a, b);
    a = x; b = x; plswap32(a, b); x = fmaxf(a, b);
    return x;
}
__device__ __forceinline__ float rsum_all(float x) { return rsum_hi(rsum_lo(x)); }
__device__ __forceinline__ float rmax_all(float x) { return rmax_hi(rmax_lo(x)); }

// pure-register 5-way select on wave-uniform sv
__device__ __forceinline__ float ksel5(float k0, float k1, float k2, float k3, float k4, int sv) {
    float r = k0;
    r = (sv == 1) ? k1 : r;
    r = (sv == 2) ? k2 : r;
    r = (sv == 3) ? k3 : r;
    r = (sv == 4) ? k4 : r;
    return r;
}

#define PIN(v) asm volatile("" : "+v"(v))

// ---------------- fused fwd+bwd scan: blocks [0,512) fwd, [512,1024) bwd ----------------
__global__ __launch_bounds__(64) void scan_kernel(
    const int* __restrict__ s, const int* __restrict__ x, const float* __restrict__ mask,
    const float* __restrict__ pi, const float* __restrict__ P, const float* __restrict__ K,
    float* __restrict__ alpha, float* __restrict__ loglik, float* __restrict__ betaRaw)
{
    const int blk = blockIdx.x, l = threadIdx.x;
    const int lo = l & 7, hi = l >> 3;
    const bool isF = blk < BB;
    const int b = isF ? blk : blk - BB;
    const int base = b * TT;

    float kN0 = K[0*64 + l],         kN1 = K[1*64 + l],         kN2 = K[2*64 + l],
          kN3 = K[3*64 + l],         kN4 = K[4*64 + l];
    float kT0 = K[0*64 + lo*8 + hi], kT1 = K[1*64 + lo*8 + hi], kT2 = K[2*64 + lo*8 + hi],
          kT3 = K[3*64 + lo*8 + hi], kT4 = K[4*64 + lo*8 + hi];
    float pH0 = P[hi*2+0], pH1 = P[hi*2+1];
    float pL0 = P[lo*2+0], pL1 = P[lo*2+1];

    // packed control preload: reg r, lane l <-> t = l*16 + r ; ctrl = s | x<<3 | m<<4
    int cR[16];
#pragma unroll
    for (int r = 0; r < 16; ++r) {
        const int sv = s[base + l*16 + r];
        const int xv = x[base + l*16 + r];
        const float mv = mask[base + l*16 + r];
        cR[r] = sv | (xv << 3) | ((mv != 0.0f) ? 16 : 0);
    }
    __builtin_amdgcn_s_waitcnt(0);
#pragma unroll
    for (int r = 0; r < 16; ++r) PIN(cR[r]);   // asm-def: cannot be rematerialized
    PIN(kN0); PIN(kN1); PIN(kN2); PIN(kN3); PIN(kN4);
    PIN(kT0); PIN(kT1); PIN(kT2); PIN(kT3); PIN(kT4);
    PIN(pH0); PIN(pH1); PIN(pL0); PIN(pL1);

    if (isF) {
        // ---------- forward ----------
        float av_lo = pi[lo];          // a[state=lo], replicated over hi
        float av_hi = pi[hi];          // a[state=hi], replicated over lo
        float c = 0.0f;
        float ms0 = rmax_lo(av_lo);
        float rs0 = __builtin_amdgcn_rcpf(ms0), rs1 = rs0;
        float lm0 = __logf(ms0),               lm1 = lm0;
        float* aptr = alpha + (size_t)base * 8;
        for (int tq = 0; tq < 64; ++tq) {
            float val0 = 0.0f, val1 = 0.0f;
#pragma unroll
            for (int r = 0; r < 16; ++r) {
                const int cw  = __builtin_amdgcn_readlane(cR[r], tq);
                const int sv  = cw & 7;
                const int xnz = cw & 8;
                const int mnz = cw & 16;
                const float kvN = ksel5(kN0,kN1,kN2,kN3,kN4, sv);
                const float kvT = ksel5(kT0,kT1,kT2,kT3,kT4, sv);
                const float pxl = xnz ? pL1 : pL0;
                const float pxh = xnz ? pH1 : pH0;
                const float nl = rsum_hi(av_hi * kvT) * (pxl * rs0);
                const float nh = rsum_lo(av_lo * kvN) * (pxh * rs0);
                av_lo = mnz ? nl : av_lo;
                av_hi = mnz ? nh : av_hi;
                c     = mnz ? (c + lm0) : c;
                rs0 = rs1; lm0 = lm1;
                const float ms = rmax_lo(av_lo);
                rs1 = __builtin_amdgcn_rcpf(ms);
                lm1 = __logf(ms);
                const float la = __logf(av_lo) + c;
                if (r < 8) val0 = (hi == r)     ? la : val0;
                else       val1 = (hi == r - 8) ? la : val1;
            }
            aptr[l] = val0; aptr[64 + l] = val1; aptr += 128;
        }
        const float laf = __logf(av_lo) + c;
        const float mm  = rmax_lo(laf);
        const float e   = rsum_lo(__expf(laf - mm));
        if (l == 0) loglik[b] = mm + __logf(e);
    } else {
        // ---------- backward (stores RAW log-beta; normalized later) ----------
        float bv_lo = 1.0f, bv_hi = 1.0f, c = 0.0f;
        float rs0 = 1.0f, rs1 = 1.0f, lm0 = 0.0f, lm1 = 0.0f;
        int sx = 0;       // packed carried s|x<<3 of last masked step
        int m1 = 0;       // mask[t+1] flag (0 for the t=1023 iteration -> pure carry)
        float* bptr = betaRaw + (size_t)(base + TT - 16) * 8;
        for (int tq = 63; tq >= 0; --tq) {
            float val0 = 0.0f, val1 = 0.0f;
#pragma unroll
            for (int rr = 0; rr < 16; ++rr) {
                const int r = 15 - rr;
                const int cw  = __builtin_amdgcn_readlane(cR[r], tq);
                const int sn  = sx & 7;
                const int xnz = sx & 8;
                const float kvN = ksel5(kN0,kN1,kN2,kN3,kN4, sn);
                const float kvT = ksel5(kT0,kT1,kT2,kT3,kT4, sn);
                const float pl = xnz ? pL1 : pL0;   // P[i=lo][xn]
                const float ph = xnz ? pH1 : pH0;   // P[i=hi][xn]
                const float nl = rsum_hi(bv_hi * ph * kvN) * rs0;  // bt[j=lo]
                const float nh = rsum_lo(bv_lo * pl * kvT) * rs0;  // bt[j=hi]
                bv_lo = m1 ? nl : bv_lo;
                bv_hi = m1 ? nh : bv_hi;
                c     = m1 ? (c + lm0) : c;
                rs0 = rs1; lm0 = lm1;
                const float ms = rmax_lo(bv_lo);
                rs1 = __builtin_amdgcn_rcpf(ms);
                lm1 = __logf(ms);
                const float lb = __logf(bv_lo) + c;
                if (r < 8) val0 = (hi == r)     ? lb : val0;
                else       val1 = (hi == r - 8) ? lb : val1;
                // carry update with THIS step's mask (m0)
                sx = (cw & 16) ? (cw & 15) : sx;
                m1 = cw & 16;
            }
            bptr[l] = val0; bptr[64 + l] = val1; bptr -= 128;
        }
    }
}

// ---------------- beta normalize: beta[b,t,z] -= loglik[b] ----------------
__global__ __launch_bounds__(256) void norm_kernel(float* __restrict__ beta,
                                                   const float* __restrict__ loglik)
{
    const int i4 = blockIdx.x * 256 + threadIdx.x;      // 1,048,576 float4s
    const int b = i4 >> 11;                             // 2048 float4 per b
    const float ll = loglik[b];
    float4* p = reinterpret_cast<float4*>(beta) + i4;
    float4 v = *p;
    v.x -= ll; v.y -= ll; v.z -= ll; v.w -= ll;
    *p = v;
}

// ---------------- gamma + xi: one wave per (b,t), all-VALU reductions ----------------
__global__ __launch_bounds__(256) void post_kernel(
    const int* __restrict__ s, const int* __restrict__ x, const float* __restrict__ mask,
    const float* __restrict__ P, const float* __restrict__ K,
    const float* __restrict__ alpha, const float* __restrict__ beta,
    float* __restrict__ gamma, float* __restrict__ xi)
{
    const int tid = threadIdx.x;
    const int w = blockIdx.x * 4 + (tid >> 6);
    const int l = tid & 63;
    const int b = w >> 10;          // T = 1024
    const int t = w & (TT - 1);
    const int lo = l & 7, hi = l >> 3;
    const int bt = b * TT + t;
    const int bt8 = bt * 8;
    const float aLo = alpha[bt8 + lo];
    const float bLo = beta[bt8 + lo];
    const float m0 = mask[bt];
    const float gv = aLo + bLo;
    const float mg = rmax_lo(gv);
    const float eg = rsum_lo(__expf(gv - mg));
    const float g = (m0 != 0.0f) ? (gv - (mg + __logf(eg))) : NINF;
    if (hi == 0) gamma[bt8 + lo] = g;
    if (t < TT - 1) {
        const float m1 = mask[bt + 1];
        const int sv = s[bt];
        const int xv = x[bt + 1];
        const float aHi = alpha[bt8 + hi];        // log_alpha[t][i], i=hi
        const float bN  = beta[bt8 + 8 + lo];     // log_beta[t+1][j], j=lo (norm cancels)
        const float lpx = __logf(P[lo*2 + xv]);   // logP[z=j][x_{t+1}]
        const float lk  = __logf(K[sv*64 + l]);   // logK[s_t][i][j]
        float v = lk + aHi + bN + lpx;
        const float mv = rmax_all(v);
        const float ev = rsum_all(__expf(v - mv));
        const float xo = (m1 != 0.0f) ? (v - (mv + __logf(ev))) : NINF;
        xi[(size_t)(b*(TT-1) + t)*64 + l] = xo;
    }
}

extern "C" void kernel_launch(void* const* d_in, const int* in_sizes, int n_in,
                              void* d_out, int out_size, void* d_ws, size_t ws_size,
                              hipStream_t stream) {
    const int*   s    = (const int*)d_in[0];
    const int*   x    = (const int*)d_in[1];
    const float* mask = (const float*)d_in[2];
    const float* pi   = (const float*)d_in[3];
    const float* P    = (const float*)d_in[4];
    const float* K    = (const float*)d_in[5];

    float* out    = (float*)d_out;
    float* gamma  = out;                                  // (B,T,Z)
    float* xi     = gamma + (size_t)BB * TT * 8;          // (B,T-1,Z,Z)
    float* alpha  = xi + (size_t)BB * (TT - 1) * 64;      // (B,T,Z)
    float* beta   = alpha + (size_t)BB * TT * 8;          // (B,T,Z)
    float* loglik = beta + (size_t)BB * TT * 8;           // (B,)

    scan_kernel<<<2 * BB, 64, 0, stream>>>(s, x, mask, pi, P, K, alpha, loglik, beta);
    norm_kernel<<<(BB * TT * 8 / 4) / 256, 256, 0, stream>>>(beta, loglik);
    post_kernel<<<BB * TT / 4, 256, 0, stream>>>(s, x, mask, P, K, alpha, beta, gamma, xi);
}

// Round 6
// 374.634 us; speedup vs baseline: 2.6369x; 1.0795x over previous
//
#include <hip/hip_runtime.h>

#define BB 512
#define TT 1024
#define NINF -10000000000.0f

// DPP ctrls: quad_perm xor1=0xB1, xor2=0x4E; row_half_mirror(^7)=0x141; row_ror:8(^8)=0x128
template<int CTRL>
__device__ __forceinline__ float dppf(float x) {
    return __builtin_bit_cast(float, __builtin_amdgcn_update_dpp(
        0, __builtin_bit_cast(int, x), CTRL, 0xF, 0xF, true));
}
__device__ __forceinline__ void plswap16(float &a, float &b) {
    asm volatile("s_nop 1\n\tv_permlane16_swap_b32 %0, %1" : "+v"(a), "+v"(b));
}
__device__ __forceinline__ void plswap32(float &a, float &b) {
    asm volatile("s_nop 1\n\tv_permlane32_swap_b32 %0, %1" : "+v"(a), "+v"(b));
}

// 8-lane-group butterfly reduce (^1, ^2, ^7) — replicated to all 8 lanes
__device__ __forceinline__ float gsum8(float x) {
    x += dppf<0xB1>(x); x += dppf<0x4E>(x); x += dppf<0x141>(x); return x;
}
__device__ __forceinline__ float gmax8(float x) {
    x = fmaxf(x, dppf<0xB1>(x)); x = fmaxf(x, dppf<0x4E>(x)); x = fmaxf(x, dppf<0x141>(x)); return x;
}
// full-wave reduce for post_kernel
__device__ __forceinline__ float rsum_hi(float x) {
    x += dppf<0x128>(x);
    float a = x, b = x; plswap16(a, b); x = a + b;
    a = x; b = x; plswap32(a, b); x = a + b;
    return x;
}
__device__ __forceinline__ float rmax_hi(float x) {
    x = fmaxf(x, dppf<0x128>(x));
    float a = x, b = x; plswap16(a, b); x = fmaxf(a, b);
    a = x; b = x; plswap32(a, b); x = fmaxf(a, b);
    return x;
}
__device__ __forceinline__ float rsum_all(float x) { return rsum_hi(gsum8(x)); }
__device__ __forceinline__ float rmax_all(float x) { return rmax_hi(gmax8(x)); }

#define PIN(v) asm volatile("" : "+v"(v))

// 5-way select from preloaded K-register file, selector SV is a (group-uniform) VGPR
#define KSEL(KARR, RR, SV) ({ float _k = KARR[0][RR];      \
    _k = ((SV)==1) ? KARR[1][RR] : _k;                     \
    _k = ((SV)==2) ? KARR[2][RR] : _k;                     \
    _k = ((SV)==3) ? KARR[3][RR] : _k;                     \
    _k = ((SV)==4) ? KARR[4][RR] : _k; _k; })

// ---------------- 8-sequences-per-wave scan: blocks [0,64) fwd, [64,128) bwd ----------------
__global__ __launch_bounds__(64) void scan8_kernel(
    const int* __restrict__ s, const int* __restrict__ x, const float* __restrict__ mask,
    const float* __restrict__ pi, const float* __restrict__ P, const float* __restrict__ K,
    float* __restrict__ alpha, float* __restrict__ loglik, float* __restrict__ betaRaw)
{
    const int blk = blockIdx.x, l = threadIdx.x;
    const int lo = l & 7, g = l >> 3;
    const bool isF = blk < 64;
    const int b = ((isF ? blk : blk - 64) << 3) + g;   // 8 sequences per wave
    const int bbase = b * TT;
    const float pL0 = P[lo*2 + 0], pL1 = P[lo*2 + 1];  // P[state=lo][x]

    if (isF) {
        // kP[s][r] = K[s][i=lo][j=lo^r]
        float kP[5][8];
#pragma unroll
        for (int ss = 0; ss < 5; ++ss)
#pragma unroll
            for (int r = 0; r < 8; ++r) kP[ss][r] = K[ss*64 + lo*8 + (lo ^ r)];
#pragma unroll
        for (int ss = 0; ss < 5; ++ss)
#pragma unroll
            for (int r = 0; r < 8; ++r) PIN(kP[ss][r]);

        // rolling 8-deep control prefetch (group-uniform addresses)
        int sB[8], xB[8]; float mB[8];
#pragma unroll
        for (int r = 0; r < 8; ++r) { sB[r] = s[bbase+r]; xB[r] = x[bbase+r]; mB[r] = mask[bbase+r]; }

        float av = pi[lo];
        float ms = gmax8(av);
        float rs0 = __builtin_amdgcn_rcpf(ms), rs1 = rs0;
        float lm0 = __logf(ms), lm1 = lm0;
        float c = 0.0f;
        int aoff = bbase*8 + lo;
        for (int tw = 0; tw < 128; ++tw) {
#pragma unroll
            for (int r = 0; r < 8; ++r) {
                const int t = tw*8 + r;
                const int svv = sB[r];
                const int xvv = xB[r];
                const float mvv = mB[r];
                int tn = t + 8; tn = (tn > TT-1) ? (TT-1) : tn;
                sB[r] = s[bbase+tn]; xB[r] = x[bbase+tn]; mB[r] = mask[bbase+tn];
                // all-gather av over the 8-lane group: ar = av[lo^r]
                const float a0 = av;
                const float a1 = dppf<0xB1>(a0);
                const float a7 = dppf<0x141>(a0);
                const float a6 = dppf<0xB1>(a7);
                const float a2 = dppf<0x4E>(a0);
                const float a3 = dppf<0x4E>(a1);
                const float a5 = dppf<0x4E>(a7);
                const float a4 = dppf<0x4E>(a6);
                // new[i] = (sum_j K[s][i,j] av[j]) * P[i][x] * rs0
                float accA = KSEL(kP,0,svv) * a0;
                accA = fmaf(KSEL(kP,1,svv), a1, accA);
                accA = fmaf(KSEL(kP,2,svv), a2, accA);
                accA = fmaf(KSEL(kP,3,svv), a3, accA);
                float accB = KSEL(kP,4,svv) * a4;
                accB = fmaf(KSEL(kP,5,svv), a5, accB);
                accB = fmaf(KSEL(kP,6,svv), a6, accB);
                accB = fmaf(KSEL(kP,7,svv), a7, accB);
                const float px = xvv ? pL1 : pL0;
                const float nv = (accA + accB) * px * rs0;
                const bool m = (mvv != 0.0f);
                av = m ? nv : av;
                c  = m ? (c + lm0) : c;
                rs0 = rs1; lm0 = lm1;
                const float ms2 = gmax8(av);
                rs1 = __builtin_amdgcn_rcpf(ms2);
                lm1 = __logf(ms2);
                alpha[aoff] = __logf(av) + c;   // log-alpha, exact bookkeeping
                aoff += 8;
            }
        }
        const float la = __logf(av) + c;
        const float gm = gmax8(la);
        const float ge = gsum8(__expf(la - gm));
        if (lo == 0) loglik[b] = gm + __logf(ge);
    } else {
        // kPT[s][r] = K[s][i=lo^r][j=lo]
        float kPT[5][8];
#pragma unroll
        for (int ss = 0; ss < 5; ++ss)
#pragma unroll
            for (int r = 0; r < 8; ++r) kPT[ss][r] = K[ss*64 + (lo ^ r)*8 + lo];
#pragma unroll
        for (int ss = 0; ss < 5; ++ss)
#pragma unroll
            for (int r = 0; r < 8; ++r) PIN(kPT[ss][r]);

        int sB[8], xB[8]; float mB[8];
#pragma unroll
        for (int r = 0; r < 8; ++r) {
            sB[r] = s[bbase + TT-8 + r]; xB[r] = x[bbase + TT-8 + r]; mB[r] = mask[bbase + TT-8 + r];
        }
        float bv = 1.0f, c = 0.0f;
        float rs0 = 1.0f, rs1 = 1.0f, lm0 = 0.0f, lm1 = 0.0f;
        int sxc = 0, m1i = 0;       // carried s|x<<3 and mask[t+1] flag (R5-verified semantics)
        int boff = (bbase + TT - 1)*8 + lo;
        for (int tw = 127; tw >= 0; --tw) {
#pragma unroll
            for (int r = 7; r >= 0; --r) {
                const int t = tw*8 + r;
                const int svv = sB[r];
                const int xvv = xB[r];
                const float mvv = mB[r];
                int tn = t - 8; tn = (tn < 0) ? 0 : tn;
                sB[r] = s[bbase+tn]; xB[r] = x[bbase+tn]; mB[r] = mask[bbase+tn];
                // bt[j] = sum_i P[i][xn]*bn[i]*K[sn][i,j]
                const float pn = (sxc & 8) ? pL1 : pL0;
                const float u0 = pn * bv;
                const float u1 = dppf<0xB1>(u0);
                const float u7 = dppf<0x141>(u0);
                const float u6 = dppf<0xB1>(u7);
                const float u2 = dppf<0x4E>(u0);
                const float u3 = dppf<0x4E>(u1);
                const float u5 = dppf<0x4E>(u7);
                const float u4 = dppf<0x4E>(u6);
                const int sn = sxc & 7;
                float accA = KSEL(kPT,0,sn) * u0;
                accA = fmaf(KSEL(kPT,1,sn), u1, accA);
                accA = fmaf(KSEL(kPT,2,sn), u2, accA);
                accA = fmaf(KSEL(kPT,3,sn), u3, accA);
                float accB = KSEL(kPT,4,sn) * u4;
                accB = fmaf(KSEL(kPT,5,sn), u5, accB);
                accB = fmaf(KSEL(kPT,6,sn), u6, accB);
                accB = fmaf(KSEL(kPT,7,sn), u7, accB);
                const float nv = (accA + accB) * rs0;
                const bool m1 = (m1i != 0);
                bv = m1 ? nv : bv;
                c  = m1 ? (c + lm0) : c;
                rs0 = rs1; lm0 = lm1;
                const float ms2 = gmax8(bv);
                rs1 = __builtin_amdgcn_rcpf(ms2);
                lm1 = __logf(ms2);
                betaRaw[boff] = __logf(bv) + c;   // RAW log-beta (normalized by norm_kernel)
                boff -= 8;
                // carry update with THIS step's controls
                const bool m0 = (mvv != 0.0f);
                sxc = m0 ? (svv | (xvv << 3)) : sxc;
                m1i = m0 ? 1 : 0;
            }
        }
    }
}

// ---------------- beta normalize: beta[b,t,z] -= loglik[b] ----------------
__global__ __launch_bounds__(256) void norm_kernel(float* __restrict__ beta,
                                                   const float* __restrict__ loglik)
{
    const int i4 = blockIdx.x * 256 + threadIdx.x;      // 1,048,576 float4s
    const int b = i4 >> 11;                             // 2048 float4 per b
    const float ll = loglik[b];
    float4* p = reinterpret_cast<float4*>(beta) + i4;
    float4 v = *p;
    v.x -= ll; v.y -= ll; v.z -= ll; v.w -= ll;
    *p = v;
}

// ---------------- gamma + xi: one wave per (b,t), all-VALU reductions ----------------
__global__ __launch_bounds__(256) void post_kernel(
    const int* __restrict__ s, const int* __restrict__ x, const float* __restrict__ mask,
    const float* __restrict__ P, const float* __restrict__ K,
    const float* __restrict__ alpha, const float* __restrict__ beta,
    float* __restrict__ gamma, float* __restrict__ xi)
{
    const int tid = threadIdx.x;
    const int w = blockIdx.x * 4 + (tid >> 6);
    const int l = tid & 63;
    const int b = w >> 10;          // T = 1024
    const int t = w & (TT - 1);
    const int lo = l & 7, hi = l >> 3;
    const int bt = b * TT + t;
    const int bt8 = bt * 8;
    const float aLo = alpha[bt8 + lo];
    const float bLo = beta[bt8 + lo];
    const float m0 = mask[bt];
    const float gv = aLo + bLo;
    const float mg = gmax8(gv);
    const float eg = gsum8(__expf(gv - mg));
    const float g = (m0 != 0.0f) ? (gv - (mg + __logf(eg))) : NINF;
    if (hi == 0) gamma[bt8 + lo] = g;
    if (t < TT - 1) {
        const float m1 = mask[bt + 1];
        const int sv = s[bt];
        const int xv = x[bt + 1];
        const float aHi = alpha[bt8 + hi];        // log_alpha[t][i], i=hi
        const float bN  = beta[bt8 + 8 + lo];     // log_beta[t+1][j], j=lo (norm cancels)
        const float lpx = __logf(P[lo*2 + xv]);   // logP[z=j][x_{t+1}]
        const float lk  = __logf(K[sv*64 + l]);   // logK[s_t][i][j]
        float v = lk + aHi + bN + lpx;
        const float mv = rmax_all(v);
        const float ev = rsum_all(__expf(v - mv));
        const float xo = (m1 != 0.0f) ? (v - (mv + __logf(ev))) : NINF;
        xi[(size_t)(b*(TT-1) + t)*64 + l] = xo;
    }
}

extern "C" void kernel_launch(void* const* d_in, const int* in_sizes, int n_in,
                              void* d_out, int out_size, void* d_ws, size_t ws_size,
                              hipStream_t stream) {
    const int*   s    = (const int*)d_in[0];
    const int*   x    = (const int*)d_in[1];
    const float* mask = (const float*)d_in[2];
    const float* pi   = (const float*)d_in[3];
    const float* P    = (const float*)d_in[4];
    const float* K    = (const float*)d_in[5];

    float* out    = (float*)d_out;
    float* gamma  = out;                                  // (B,T,Z)
    float* xi     = gamma + (size_t)BB * TT * 8;          // (B,T-1,Z,Z)
    float* alpha  = xi + (size_t)BB * (TT - 1) * 64;      // (B,T,Z)
    float* beta   = alpha + (size_t)BB * TT * 8;          // (B,T,Z)
    float* loglik = beta + (size_t)BB * TT * 8;           // (B,)

    scan8_kernel<<<128, 64, 0, stream>>>(s, x, mask, pi, P, K, alpha, loglik, beta);
    norm_kernel<<<(BB * TT * 8 / 4) / 256, 256, 0, stream>>>(beta, loglik);
    post_kernel<<<BB * TT / 4, 256, 0, stream>>>(s, x, mask, P, K, alpha, beta, gamma, xi);
}

// Round 7
// 263.228 us; speedup vs baseline: 3.7529x; 1.4232x over previous
//
#include <hip/hip_runtime.h>

#define BB 512
#define TT 1024
#define NINF -10000000000.0f
#define CSL 1032   // ctrl slots: time t stored at slot t+4, t in [-4, 1028)

// DPP ctrls: quad_perm xor1=0xB1, xor2=0x4E; row_half_mirror(^7)=0x141; row_ror:8(^8)=0x128
template<int CTRL>
__device__ __forceinline__ float dppf(float x) {
    return __builtin_bit_cast(float, __builtin_amdgcn_update_dpp(
        0, __builtin_bit_cast(int, x), CTRL, 0xF, 0xF, true));
}
__device__ __forceinline__ void plswap16(float &a, float &b) {
    asm volatile("s_nop 1\n\tv_permlane16_swap_b32 %0, %1" : "+v"(a), "+v"(b));
}
__device__ __forceinline__ void plswap32(float &a, float &b) {
    asm volatile("s_nop 1\n\tv_permlane32_swap_b32 %0, %1" : "+v"(a), "+v"(b));
}

// 8-lane-group butterfly reduce (^1, ^2, ^7) — replicated to all 8 lanes
__device__ __forceinline__ float gsum8(float x) {
    x += dppf<0xB1>(x); x += dppf<0x4E>(x); x += dppf<0x141>(x); return x;
}
__device__ __forceinline__ float gmax8(float x) {
    x = fmaxf(x, dppf<0xB1>(x)); x = fmaxf(x, dppf<0x4E>(x)); x = fmaxf(x, dppf<0x141>(x)); return x;
}
// full-wave reduce for post_kernel
__device__ __forceinline__ float rsum_hi(float x) {
    x += dppf<0x128>(x);
    float a = x, b = x; plswap16(a, b); x = a + b;
    a = x; b = x; plswap32(a, b); x = a + b;
    return x;
}
__device__ __forceinline__ float rmax_hi(float x) {
    x = fmaxf(x, dppf<0x128>(x));
    float a = x, b = x; plswap16(a, b); x = fmaxf(a, b);
    a = x; b = x; plswap32(a, b); x = fmaxf(a, b);
    return x;
}
__device__ __forceinline__ float rsum_all(float x) { return rsum_hi(gsum8(x)); }
__device__ __forceinline__ float rmax_all(float x) { return rmax_hi(gmax8(x)); }

// ---------------- 8-sequences-per-wave scan: blocks [0,64) fwd, [64,128) bwd ----------------
// All in-loop memory: 1 ds_read ctrl (4-deep prefetch) + 2 ds_read_b128 K-row
// (2-deep prefetch) + 1 fire-and-forget global store. No vmcnt waits in loop.
__global__ __launch_bounds__(64) void scan8_kernel(
    const int* __restrict__ s, const int* __restrict__ x, const float* __restrict__ mask,
    const float* __restrict__ pi, const float* __restrict__ P, const float* __restrict__ K,
    float* __restrict__ alpha, float* __restrict__ loglik, float* __restrict__ betaRaw)
{
    __shared__ int    ctrlL[CSL * 8];  // [slot][g]
    __shared__ float4 kX4[5 * 17];     // fwd: word s*68 + i*8 + r = K[s][i][i^r]  (272B stride)
    __shared__ float4 kT4[5 * 17];     // bwd: word s*68 + i*8 + r = K[s][i^r][i]

    const int blk = blockIdx.x, l = threadIdx.x;
    const int lo = l & 7, g = l >> 3;
    const bool isF = blk < 64;
    const int bfirst = (isF ? blk : blk - 64) << 3;
    const int b = bfirst + g;
    const int bbase = b * TT;

    // ---- stage K tables (xor layout) ----
    {
        const int row = l >> 3, r = l & 7;
        float* kXf = (float*)kX4; float* kTf = (float*)kT4;
#pragma unroll
        for (int ss = 0; ss < 5; ++ss) {
            kXf[ss*68 + l] = K[ss*64 + row*8 + (row ^ r)];
            kTf[ss*68 + l] = K[ss*64 + (row ^ r)*8 + row];
        }
    }
    // ---- stage packed control ----
    if (l < 32) { ctrlL[l] = 0; ctrlL[8224 + l] = 0; }     // front/back pads
    for (int it = 0; it < 32; ++it) {
        const int e4 = it*64 + l;              // 2048 quad-entries
        const int gg = e4 & 7;
        const int t0 = (e4 >> 3) * 4;
        const int4   s4 = *reinterpret_cast<const int4*>(&s[(bfirst+gg)*TT + t0]);
        const int4   x4 = *reinterpret_cast<const int4*>(&x[(bfirst+gg)*TT + t0]);
        const float4 m4 = *reinterpret_cast<const float4*>(&mask[(bfirst+gg)*TT + t0]);
        ctrlL[(t0+4)*8 + gg] = s4.x | (x4.x << 3) | ((m4.x != 0.f) ? 16 : 0);
        ctrlL[(t0+5)*8 + gg] = s4.y | (x4.y << 3) | ((m4.y != 0.f) ? 16 : 0);
        ctrlL[(t0+6)*8 + gg] = s4.z | (x4.z << 3) | ((m4.z != 0.f) ? 16 : 0);
        ctrlL[(t0+7)*8 + gg] = s4.w | (x4.w << 3) | ((m4.w != 0.f) ? 16 : 0);
    }
    __syncthreads();

    const float pL0 = P[lo*2 + 0], pL1 = P[lo*2 + 1];  // P[state=lo][x]
    const int* cp = &ctrlL[g];

    if (isF) {
        // ---------- forward ----------
        const float4* kb = ((const float4*)kX4) + lo*2;
        float av = pi[lo];
        float c = 0.0f;
        float ms0 = gmax8(av);
        float rs0 = __builtin_amdgcn_rcpf(ms0), lm0 = __logf(ms0);
        int cR0 = cp[32], cR1 = cp[40], cR2 = cp[48], cR3 = cp[56];   // t=0..3
        const int sva = cR0 & 7, svb = cR1 & 7;
        float4 kE0 = kb[sva*17], kE1 = kb[sva*17 + 1];   // K(t even)
        float4 kO0 = kb[svb*17], kO1 = kb[svb*17 + 1];   // K(t odd)
        int aoff = bbase*8 + lo;
        for (int tq = 0; tq < 256; ++tq) {
            // quad-boundary rescale (1-stale, off critical path)
            av *= rs0; c += lm0;
            const float msq = gmax8(av);
            rs0 = __builtin_amdgcn_rcpf(msq); lm0 = __logf(msq);
            const int* cpt = cp + tq*32;
#pragma unroll
            for (int r = 0; r < 4; ++r) {
                int cw;
                if      (r == 0) { cw = cR0; cR0 = cpt[64]; }   // refill with t+4
                else if (r == 1) { cw = cR1; cR1 = cpt[72]; }
                else if (r == 2) { cw = cR2; cR2 = cpt[80]; }
                else             { cw = cR3; cR3 = cpt[88]; }
                float4 k0, k1;
                if (r & 1) { k0 = kO0; k1 = kO1; } else { k0 = kE0; k1 = kE1; }
                // prefetch K(t+2): its ctrl sits in slot (r+2)&3 (verified rotation)
                int cw2;
                if      (r == 0) cw2 = cR2;
                else if (r == 1) cw2 = cR3;
                else if (r == 2) cw2 = cR0;
                else             cw2 = cR1;
                const int sv2 = cw2 & 7;
                const float4 kn0 = kb[sv2*17], kn1 = kb[sv2*17 + 1];
                if (r & 1) { kO0 = kn0; kO1 = kn1; } else { kE0 = kn0; kE1 = kn1; }
                // all-gather av over the group: a_r = av[lo^r]
                const float a0 = av;
                const float a1 = dppf<0xB1>(a0);
                const float a2 = dppf<0x4E>(a0);
                const float a7 = dppf<0x141>(a0);
                const float a3 = dppf<0x4E>(a1);
                const float a6 = dppf<0xB1>(a7);
                const float a5 = dppf<0x4E>(a7);
                const float a4 = dppf<0x4E>(a6);
                float accA = k0.x * a0;
                accA = fmaf(k0.y, a1, accA);
                accA = fmaf(k0.z, a2, accA);
                accA = fmaf(k0.w, a3, accA);
                float accB = k1.x * a4;
                accB = fmaf(k1.y, a5, accB);
                accB = fmaf(k1.z, a6, accB);
                accB = fmaf(k1.w, a7, accB);
                const float px = (cw & 8) ? pL1 : pL0;
                const float nv = (accA + accB) * px;
                av = (cw & 16) ? nv : av;
                alpha[aoff] = __logf(av) + c;
                aoff += 8;
            }
        }
        const float la = __logf(av) + c;
        const float gm = gmax8(la);
        const float ge = gsum8(__expf(la - gm));
        if (lo == 0) loglik[b] = gm + __logf(ge);
    } else {
        // ---------- backward (stores RAW log-beta; norm_kernel subtracts ll) ----------
        const float4* kb = ((const float4*)kT4) + lo*2;
        float bv = 1.0f, c = 0.0f;
        float rs0 = 1.0f, lm0 = 0.0f;
        int sxc = 0, m1 = 0;
        int cR0 = cp[8192], cR1 = cp[8200], cR2 = cp[8208], cR3 = cp[8216]; // t=1020..1023
        float4 kE0 = kb[0], kE1 = kb[1];   // overwritten before first even-t use
        float4 kO0 = kb[0], kO1 = kb[1];   // t=1023: sn=0, result unused (m1=0)
        int boff = (bbase + TT - 1)*8 + lo;
        for (int tq = 255; tq >= 0; --tq) {
            bv *= rs0; c += lm0;
            const float msq = gmax8(bv);
            rs0 = __builtin_amdgcn_rcpf(msq); lm0 = __logf(msq);
            const int* cpt = cp + tq*32;
#pragma unroll
            for (int rr = 0; rr < 4; ++rr) {
                const int r = 3 - rr;          // t = tq*4 + r, descending
                int cw;
                if      (r == 3) { cw = cR3; cR3 = cpt[24]; }   // refill with t-4
                else if (r == 2) { cw = cR2; cR2 = cpt[16]; }
                else if (r == 1) { cw = cR1; cR1 = cpt[8];  }
                else             { cw = cR0; cR0 = cpt[0];  }
                float4 k0, k1;
                if (r & 1) { k0 = kO0; k1 = kO1; } else { k0 = kE0; k1 = kE1; }
                // bt[j=lo] = sum_i P[i][xn]*bn[i]*K[sn][i][lo], xor-gathered
                const float pn = (sxc & 8) ? pL1 : pL0;
                const float u0 = pn * bv;
                const float u1 = dppf<0xB1>(u0);
                const float u2 = dppf<0x4E>(u0);
                const float u7 = dppf<0x141>(u0);
                const float u3 = dppf<0x4E>(u1);
                const float u6 = dppf<0xB1>(u7);
                const float u5 = dppf<0x4E>(u7);
                const float u4 = dppf<0x4E>(u6);
                float accA = k0.x * u0;
                accA = fmaf(k0.y, u1, accA);
                accA = fmaf(k0.z, u2, accA);
                accA = fmaf(k0.w, u3, accA);
                float accB = k1.x * u4;
                accB = fmaf(k1.y, u5, accB);
                accB = fmaf(k1.z, u6, accB);
                accB = fmaf(k1.w, u7, accB);
                const float nv = accA + accB;
                bv = m1 ? nv : bv;
                betaRaw[boff] = __logf(bv) + c;
                boff -= 8;
                // carry update with THIS step's controls (R5/R6-verified semantics)
                sxc = (cw & 16) ? (cw & 15) : sxc;
                m1 = cw & 16;
                // prefetch K(t-1) with the fresh carry (parity of t-1 = !(r&1))
                const int sn = sxc & 7;
                const float4 kn0 = kb[sn*17], kn1 = kb[sn*17 + 1];
                if (r & 1) { kE0 = kn0; kE1 = kn1; } else { kO0 = kn0; kO1 = kn1; }
            }
        }
    }
}

// ---------------- beta normalize: beta[b,t,z] -= loglik[b] ----------------
__global__ __launch_bounds__(256) void norm_kernel(float* __restrict__ beta,
                                                   const float* __restrict__ loglik)
{
    const int i4 = blockIdx.x * 256 + threadIdx.x;      // 1,048,576 float4s
    const int b = i4 >> 11;                             // 2048 float4 per b
    const float ll = loglik[b];
    float4* p = reinterpret_cast<float4*>(beta) + i4;
    float4 v = *p;
    v.x -= ll; v.y -= ll; v.z -= ll; v.w -= ll;
    *p = v;
}

// ---------------- gamma + xi: one wave per (b,t), all-VALU reductions ----------------
__global__ __launch_bounds__(256) void post_kernel(
    const int* __restrict__ s, const int* __restrict__ x, const float* __restrict__ mask,
    const float* __restrict__ P, const float* __restrict__ K,
    const float* __restrict__ alpha, const float* __restrict__ beta,
    float* __restrict__ gamma, float* __restrict__ xi)
{
    const int tid = threadIdx.x;
    const int w = blockIdx.x * 4 + (tid >> 6);
    const int l = tid & 63;
    const int b = w >> 10;          // T = 1024
    const int t = w & (TT - 1);
    const int lo = l & 7, hi = l >> 3;
    const int bt = b * TT + t;
    const int bt8 = bt * 8;
    const float aLo = alpha[bt8 + lo];
    const float bLo = beta[bt8 + lo];
    const float m0 = mask[bt];
    const float gv = aLo + bLo;
    const float mg = gmax8(gv);
    const float eg = gsum8(__expf(gv - mg));
    const float g = (m0 != 0.0f) ? (gv - (mg + __logf(eg))) : NINF;
    if (hi == 0) gamma[bt8 + lo] = g;
    if (t < TT - 1) {
        const float m1 = mask[bt + 1];
        const int sv = s[bt];
        const int xv = x[bt + 1];
        const float aHi = alpha[bt8 + hi];        // log_alpha[t][i], i=hi
        const float bN  = beta[bt8 + 8 + lo];     // log_beta[t+1][j], j=lo (norm cancels)
        const float lpx = __logf(P[lo*2 + xv]);   // logP[z=j][x_{t+1}]
        const float lk  = __logf(K[sv*64 + l]);   // logK[s_t][i][j]
        float v = lk + aHi + bN + lpx;
        const float mv = rmax_all(v);
        const float ev = rsum_all(__expf(v - mv));
        const float xo = (m1 != 0.0f) ? (v - (mv + __logf(ev))) : NINF;
        xi[(size_t)(b*(TT-1) + t)*64 + l] = xo;
    }
}

extern "C" void kernel_launch(void* const* d_in, const int* in_sizes, int n_in,
                              void* d_out, int out_size, void* d_ws, size_t ws_size,
                              hipStream_t stream) {
    const int*   s    = (const int*)d_in[0];
    const int*   x    = (const int*)d_in[1];
    const float* mask = (const float*)d_in[2];
    const float* pi   = (const float*)d_in[3];
    const float* P    = (const float*)d_in[4];
    const float* K    = (const float*)d_in[5];

    float* out    = (float*)d_out;
    float* gamma  = out;                                  // (B,T,Z)
    float* xi     = gamma + (size_t)BB * TT * 8;          // (B,T-1,Z,Z)
    float* alpha  = xi + (size_t)BB * (TT - 1) * 64;      // (B,T,Z)
    float* beta   = alpha + (size_t)BB * TT * 8;          // (B,T,Z)
    float* loglik = beta + (size_t)BB * TT * 8;           // (B,)

    scan8_kernel<<<128, 64, 0, stream>>>(s, x, mask, pi, P, K, alpha, loglik, beta);
    norm_kernel<<<(BB * TT * 8 / 4) / 256, 256, 0, stream>>>(beta, loglik);
    post_kernel<<<BB * TT / 4, 256, 0, stream>>>(s, x, mask, P, K, alpha, beta, gamma, xi);
}

// Round 8
// 253.474 us; speedup vs baseline: 3.8974x; 1.0385x over previous
//
#include <hip/hip_runtime.h>

#define BB 512
#define TT 1024
#define NINF -10000000000.0f
#define CSL 1032   // ctrl slots: time t stored at slot t+4, t in [-4, 1028)

// DPP ctrls: quad_perm xor1=0xB1, xor2=0x4E; row_half_mirror(^7)=0x141; row_ror:8(^8)=0x128
template<int CTRL>
__device__ __forceinline__ float dppf(float x) {
    return __builtin_bit_cast(float, __builtin_amdgcn_update_dpp(
        0, __builtin_bit_cast(int, x), CTRL, 0xF, 0xF, true));
}

// 8-lane-group butterfly reduce (^1, ^2, ^7) — replicated to all 8 lanes
__device__ __forceinline__ float gsum8(float x) {
    x += dppf<0xB1>(x); x += dppf<0x4E>(x); x += dppf<0x141>(x); return x;
}
__device__ __forceinline__ float gmax8(float x) {
    x = fmaxf(x, dppf<0xB1>(x)); x = fmaxf(x, dppf<0x4E>(x)); x = fmaxf(x, dppf<0x141>(x)); return x;
}

// ---------------- 8-sequences-per-wave scan: blocks [0,64) fwd, [64,128) bwd ----------------
// (unchanged from R7 — verified)
__global__ __launch_bounds__(64) void scan8_kernel(
    const int* __restrict__ s, const int* __restrict__ x, const float* __restrict__ mask,
    const float* __restrict__ pi, const float* __restrict__ P, const float* __restrict__ K,
    float* __restrict__ alpha, float* __restrict__ loglik, float* __restrict__ betaRaw)
{
    __shared__ int    ctrlL[CSL * 8];  // [slot][g]
    __shared__ float4 kX4[5 * 17];     // fwd: word s*68 + i*8 + r = K[s][i][i^r]  (272B stride)
    __shared__ float4 kT4[5 * 17];     // bwd: word s*68 + i*8 + r = K[s][i^r][i]

    const int blk = blockIdx.x, l = threadIdx.x;
    const int lo = l & 7, g = l >> 3;
    const bool isF = blk < 64;
    const int bfirst = (isF ? blk : blk - 64) << 3;
    const int b = bfirst + g;
    const int bbase = b * TT;

    // ---- stage K tables (xor layout) ----
    {
        const int row = l >> 3, r = l & 7;
        float* kXf = (float*)kX4; float* kTf = (float*)kT4;
#pragma unroll
        for (int ss = 0; ss < 5; ++ss) {
            kXf[ss*68 + l] = K[ss*64 + row*8 + (row ^ r)];
            kTf[ss*68 + l] = K[ss*64 + (row ^ r)*8 + row];
        }
    }
    // ---- stage packed control ----
    if (l < 32) { ctrlL[l] = 0; ctrlL[8224 + l] = 0; }     // front/back pads
    for (int it = 0; it < 32; ++it) {
        const int e4 = it*64 + l;              // 2048 quad-entries
        const int gg = e4 & 7;
        const int t0 = (e4 >> 3) * 4;
        const int4   s4 = *reinterpret_cast<const int4*>(&s[(bfirst+gg)*TT + t0]);
        const int4   x4 = *reinterpret_cast<const int4*>(&x[(bfirst+gg)*TT + t0]);
        const float4 m4 = *reinterpret_cast<const float4*>(&mask[(bfirst+gg)*TT + t0]);
        ctrlL[(t0+4)*8 + gg] = s4.x | (x4.x << 3) | ((m4.x != 0.f) ? 16 : 0);
        ctrlL[(t0+5)*8 + gg] = s4.y | (x4.y << 3) | ((m4.y != 0.f) ? 16 : 0);
        ctrlL[(t0+6)*8 + gg] = s4.z | (x4.z << 3) | ((m4.z != 0.f) ? 16 : 0);
        ctrlL[(t0+7)*8 + gg] = s4.w | (x4.w << 3) | ((m4.w != 0.f) ? 16 : 0);
    }
    __syncthreads();

    const float pL0 = P[lo*2 + 0], pL1 = P[lo*2 + 1];  // P[state=lo][x]
    const int* cp = &ctrlL[g];

    if (isF) {
        // ---------- forward ----------
        const float4* kb = ((const float4*)kX4) + lo*2;
        float av = pi[lo];
        float c = 0.0f;
        float ms0 = gmax8(av);
        float rs0 = __builtin_amdgcn_rcpf(ms0), lm0 = __logf(ms0);
        int cR0 = cp[32], cR1 = cp[40], cR2 = cp[48], cR3 = cp[56];   // t=0..3
        const int sva = cR0 & 7, svb = cR1 & 7;
        float4 kE0 = kb[sva*17], kE1 = kb[sva*17 + 1];   // K(t even)
        float4 kO0 = kb[svb*17], kO1 = kb[svb*17 + 1];   // K(t odd)
        int aoff = bbase*8 + lo;
        for (int tq = 0; tq < 256; ++tq) {
            // quad-boundary rescale (1-stale, off critical path)
            av *= rs0; c += lm0;
            const float msq = gmax8(av);
            rs0 = __builtin_amdgcn_rcpf(msq); lm0 = __logf(msq);
            const int* cpt = cp + tq*32;
#pragma unroll
            for (int r = 0; r < 4; ++r) {
                int cw;
                if      (r == 0) { cw = cR0; cR0 = cpt[64]; }   // refill with t+4
                else if (r == 1) { cw = cR1; cR1 = cpt[72]; }
                else if (r == 2) { cw = cR2; cR2 = cpt[80]; }
                else             { cw = cR3; cR3 = cpt[88]; }
                float4 k0, k1;
                if (r & 1) { k0 = kO0; k1 = kO1; } else { k0 = kE0; k1 = kE1; }
                // prefetch K(t+2): its ctrl sits in slot (r+2)&3
                int cw2;
                if      (r == 0) cw2 = cR2;
                else if (r == 1) cw2 = cR3;
                else if (r == 2) cw2 = cR0;
                else             cw2 = cR1;
                const int sv2 = cw2 & 7;
                const float4 kn0 = kb[sv2*17], kn1 = kb[sv2*17 + 1];
                if (r & 1) { kO0 = kn0; kO1 = kn1; } else { kE0 = kn0; kE1 = kn1; }
                // all-gather av over the group: a_r = av[lo^r]
                const float a0 = av;
                const float a1 = dppf<0xB1>(a0);
                const float a2 = dppf<0x4E>(a0);
                const float a7 = dppf<0x141>(a0);
                const float a3 = dppf<0x4E>(a1);
                const float a6 = dppf<0xB1>(a7);
                const float a5 = dppf<0x4E>(a7);
                const float a4 = dppf<0x4E>(a6);
                float accA = k0.x * a0;
                accA = fmaf(k0.y, a1, accA);
                accA = fmaf(k0.z, a2, accA);
                accA = fmaf(k0.w, a3, accA);
                float accB = k1.x * a4;
                accB = fmaf(k1.y, a5, accB);
                accB = fmaf(k1.z, a6, accB);
                accB = fmaf(k1.w, a7, accB);
                const float px = (cw & 8) ? pL1 : pL0;
                const float nv = (accA + accB) * px;
                av = (cw & 16) ? nv : av;
                alpha[aoff] = __logf(av) + c;
                aoff += 8;
            }
        }
        const float la = __logf(av) + c;
        const float gm = gmax8(la);
        const float ge = gsum8(__expf(la - gm));
        if (lo == 0) loglik[b] = gm + __logf(ge);
    } else {
        // ---------- backward (stores RAW log-beta; norm_kernel subtracts ll) ----------
        const float4* kb = ((const float4*)kT4) + lo*2;
        float bv = 1.0f, c = 0.0f;
        float rs0 = 1.0f, lm0 = 0.0f;
        int sxc = 0, m1 = 0;
        int cR0 = cp[8192], cR1 = cp[8200], cR2 = cp[8208], cR3 = cp[8216]; // t=1020..1023
        float4 kE0 = kb[0], kE1 = kb[1];   // overwritten before first even-t use
        float4 kO0 = kb[0], kO1 = kb[1];   // t=1023: sn=0, result unused (m1=0)
        int boff = (bbase + TT - 1)*8 + lo;
        for (int tq = 255; tq >= 0; --tq) {
            bv *= rs0; c += lm0;
            const float msq = gmax8(bv);
            rs0 = __builtin_amdgcn_rcpf(msq); lm0 = __logf(msq);
            const int* cpt = cp + tq*32;
#pragma unroll
            for (int rr = 0; rr < 4; ++rr) {
                const int r = 3 - rr;          // t = tq*4 + r, descending
                int cw;
                if      (r == 3) { cw = cR3; cR3 = cpt[24]; }   // refill with t-4
                else if (r == 2) { cw = cR2; cR2 = cpt[16]; }
                else if (r == 1) { cw = cR1; cR1 = cpt[8];  }
                else             { cw = cR0; cR0 = cpt[0];  }
                float4 k0, k1;
                if (r & 1) { k0 = kO0; k1 = kO1; } else { k0 = kE0; k1 = kE1; }
                // bt[j=lo] = sum_i P[i][xn]*bn[i]*K[sn][i][lo], xor-gathered
                const float pn = (sxc & 8) ? pL1 : pL0;
                const float u0 = pn * bv;
                const float u1 = dppf<0xB1>(u0);
                const float u2 = dppf<0x4E>(u0);
                const float u7 = dppf<0x141>(u0);
                const float u3 = dppf<0x4E>(u1);
                const float u6 = dppf<0xB1>(u7);
                const float u5 = dppf<0x4E>(u7);
                const float u4 = dppf<0x4E>(u6);
                float accA = k0.x * u0;
                accA = fmaf(k0.y, u1, accA);
                accA = fmaf(k0.z, u2, accA);
                accA = fmaf(k0.w, u3, accA);
                float accB = k1.x * u4;
                accB = fmaf(k1.y, u5, accB);
                accB = fmaf(k1.z, u6, accB);
                accB = fmaf(k1.w, u7, accB);
                const float nv = accA + accB;
                bv = m1 ? nv : bv;
                betaRaw[boff] = __logf(bv) + c;
                boff -= 8;
                // carry update with THIS step's controls
                sxc = (cw & 16) ? (cw & 15) : sxc;
                m1 = cw & 16;
                // prefetch K(t-1) with the fresh carry (parity of t-1 = !(r&1))
                const int sn = sxc & 7;
                const float4 kn0 = kb[sn*17], kn1 = kb[sn*17 + 1];
                if (r & 1) { kE0 = kn0; kE1 = kn1; } else { kO0 = kn0; kO1 = kn1; }
            }
        }
    }
}

// ---------------- beta normalize: beta[b,t,z] -= loglik[b] ----------------
__global__ __launch_bounds__(256) void norm_kernel(float* __restrict__ beta,
                                                   const float* __restrict__ loglik)
{
    const int i4 = blockIdx.x * 256 + threadIdx.x;      // 1,048,576 float4s
    const int b = i4 >> 11;                             // 2048 float4 per b
    const float ll = loglik[b];
    float4* p = reinterpret_cast<float4*>(beta) + i4;
    float4 v = *p;
    v.x -= ll; v.y -= ll; v.z -= ll; v.w -= ll;
    *p = v;
}

// ---------------- gamma + xi: streaming, NO reductions ----------------
// Forward-backward invariant: LSE_i(log_alpha[t,i] + log_beta_norm[t,i]) == 0
// for all t, and the xi normalizer equals the same quantity whenever
// mask[t+1] != 0 (the only case xi isn't NINF). So both normalizations
// are exact no-ops; gamma/xi are pure sums of table lookups.
__global__ __launch_bounds__(256) void post_kernel(
    const int* __restrict__ s, const int* __restrict__ x, const float* __restrict__ mask,
    const float* __restrict__ P, const float* __restrict__ K,
    const float* __restrict__ alpha, const float* __restrict__ beta,
    float* __restrict__ gamma, float* __restrict__ xi)
{
    __shared__ float lK[320];   // logK[s][i][j]
    __shared__ float lP[16];    // logP[z][x]
    const int tid = threadIdx.x;
    if (tid < 320) lK[tid] = __logf(K[tid]);
    if (tid < 16)  lP[tid] = __logf(P[tid]);
    __syncthreads();

    const int w = blockIdx.x * 4 + (tid >> 6);
    const int l = tid & 63;
    const int b = w >> 10;          // T = 1024
    const int t = w & (TT - 1);
    const int lo = l & 7, hi = l >> 3;
    const int bt = b * TT + t;
    const int bt8 = bt * 8;

    const float m0 = mask[bt];
    if (hi == 0) {
        const float aLo = alpha[bt8 + lo];
        const float bLo = beta[bt8 + lo];
        gamma[bt8 + lo] = (m0 != 0.0f) ? (aLo + bLo) : NINF;
    }
    if (t < TT - 1) {
        const float m1 = mask[bt + 1];
        float xo = NINF;
        if (m1 != 0.0f) {                       // wave-uniform branch
            const int sv = s[bt];
            const int xv = x[bt + 1];
            const float aHi = alpha[bt8 + hi];  // log_alpha[t][i], i=hi
            const float bN  = beta[bt8 + 8 + lo];   // log_beta_norm[t+1][j], j=lo
            xo = lK[sv*64 + l] + aHi + bN + lP[lo*2 + xv];
        }
        xi[(size_t)(b*(TT-1) + t)*64 + l] = xo;
    }
}

extern "C" void kernel_launch(void* const* d_in, const int* in_sizes, int n_in,
                              void* d_out, int out_size, void* d_ws, size_t ws_size,
                              hipStream_t stream) {
    const int*   s    = (const int*)d_in[0];
    const int*   x    = (const int*)d_in[1];
    const float* mask = (const float*)d_in[2];
    const float* pi   = (const float*)d_in[3];
    const float* P    = (const float*)d_in[4];
    const float* K    = (const float*)d_in[5];

    float* out    = (float*)d_out;
    float* gamma  = out;                                  // (B,T,Z)
    float* xi     = gamma + (size_t)BB * TT * 8;          // (B,T-1,Z,Z)
    float* alpha  = xi + (size_t)BB * (TT - 1) * 64;      // (B,T,Z)
    float* beta   = alpha + (size_t)BB * TT * 8;          // (B,T,Z)
    float* loglik = beta + (size_t)BB * TT * 8;           // (B,)

    scan8_kernel<<<128, 64, 0, stream>>>(s, x, mask, pi, P, K, alpha, loglik, beta);
    norm_kernel<<<(BB * TT * 8 / 4) / 256, 256, 0, stream>>>(beta, loglik);
    post_kernel<<<BB * TT / 4, 256, 0, stream>>>(s, x, mask, P, K, alpha, beta, gamma, xi);
}

// Round 9
// 140.834 us; speedup vs baseline: 7.0145x; 1.7998x over previous
//
#include <hip/hip_runtime.h>

#define BB 512
#define TT 1024
#define GG 32
#define LL 32
#define NINF -10000000000.0f

// DPP ctrls: quad_perm xor1=0xB1, xor2=0x4E; row_half_mirror(^7)=0x141
template<int CTRL>
__device__ __forceinline__ float dppf(float x) {
    return __builtin_bit_cast(float, __builtin_amdgcn_update_dpp(
        0, __builtin_bit_cast(int, x), CTRL, 0xF, 0xF, true));
}
// 8-lane-group butterfly reduce (^1, ^2, ^7) — replicated to all 8 lanes
__device__ __forceinline__ float gsum8(float x) {
    x += dppf<0xB1>(x); x += dppf<0x4E>(x); x += dppf<0x141>(x); return x;
}
__device__ __forceinline__ float gmax8(float x) {
    x = fmaxf(x, dppf<0xB1>(x)); x = fmaxf(x, dppf<0x4E>(x)); x = fmaxf(x, dppf<0x141>(x)); return x;
}

#define GATHER8(A0, A1, A2, A3, A4, A5, A6, A7)      \
    const float A1 = dppf<0xB1>(A0);                 \
    const float A2 = dppf<0x4E>(A0);                 \
    const float A7 = dppf<0x141>(A0);                \
    const float A3 = dppf<0x4E>(A1);                 \
    const float A6 = dppf<0xB1>(A7);                 \
    const float A5 = dppf<0x4E>(A7);                 \
    const float A4 = dppf<0x4E>(A6);

#define FMASUM(ACC, K0, K1, A0,A1,A2,A3,A4,A5,A6,A7) \
    float ACC;                                       \
    {   float accA = K0.x * A0;                      \
        accA = fmaf(K0.y, A1, accA);                 \
        accA = fmaf(K0.z, A2, accA);                 \
        accA = fmaf(K0.w, A3, accA);                 \
        float accB = K1.x * A4;                      \
        accB = fmaf(K1.y, A5, accB);                 \
        accB = fmaf(K1.z, A6, accB);                 \
        accB = fmaf(K1.w, A7, accB);                 \
        ACC = accA + accB; }

// ============ Phase A: per-segment 8x8 transfer matrices ============
// blocks [0,4096) fwd, [4096,8192) bwd; 4 tasks(waves)/block; task=(seq,seg)
// lane: group hi = matrix column (basis index), lo = state row.
__global__ __launch_bounds__(256) void segmat_kernel(
    const int* __restrict__ s, const int* __restrict__ x, const float* __restrict__ mask,
    const float* __restrict__ P, const float* __restrict__ K,
    float* __restrict__ FM, float* __restrict__ BM)
{
    __shared__ float kTab[5 * 68];   // row stride 68 floats (272B): [sv][i*8+r]
    __shared__ int   ctrlA[4][LL];
    const int tid = threadIdx.x;
    const int wv = tid >> 6, l = tid & 63;
    const int lo = l & 7, hi = l >> 3;
    const bool isF = blockIdx.x < 4096;
    const int task = (isF ? blockIdx.x : blockIdx.x - 4096) * 4 + wv;
    const int seq = task >> 5, seg = task & 31;
    const int sb = seq * TT;
    const int t0 = seg * LL;

    for (int e = tid; e < 340; e += 256) {
        const int ss = e / 68, idx = e - ss * 68;
        float v = 0.0f;
        if (idx < 64) {
            const int row = idx >> 3, r = idx & 7;
            v = isF ? K[ss*64 + row*8 + (row ^ r)]      // K[s][i][i^r]
                    : K[ss*64 + (row ^ r)*8 + row];     // K[s][i^r][i]
        }
        kTab[e] = v;
    }
    if (l < LL) {
        const int tt = t0 + l;
        ctrlA[wv][l] = s[sb+tt] | (x[sb+tt] << 3) | ((mask[sb+tt] != 0.0f) ? 16 : 0);
    }
    __syncthreads();

    const float pL0 = P[lo*2+0], pL1 = P[lo*2+1];
    const float* kbase = kTab + lo*8;
    float av = (lo == hi) ? 1.0f : 0.0f;   // identity column hi
    float c = 0.0f;

    if (isF) {
#pragma unroll 4
        for (int u = 0; u < LL; ++u) {
            const int cw = __builtin_amdgcn_readfirstlane(ctrlA[wv][u]);
            if (cw & 16) {
                const float* kp = kbase + (cw & 7) * 68;
                const float4 k0 = *(const float4*)kp;
                const float4 k1 = *(const float4*)(kp + 4);
                const float a0 = av;
                GATHER8(a0, a1, a2, a3, a4, a5, a6, a7)
                FMASUM(acc, k0, k1, a0,a1,a2,a3,a4,a5,a6,a7)
                av = acc * ((cw & 8) ? pL1 : pL0);
            }
            if ((u & 3) == 3) {
                const float ms = gmax8(av);
                av *= __builtin_amdgcn_rcpf(ms);
                c += __logf(ms);
            }
        }
        FM[task*64 + l] = __logf(av) + c;
    } else {
        // incoming carry: sxc = (s,x) at smallest masked t'' >= t1; m1 = mask[t1]
        const int t1 = t0 + LL;
        int sxc = 0;
        for (int tt = t1; tt < TT; ++tt) {
            if (mask[sb + tt] != 0.0f) { sxc = s[sb+tt] | (x[sb+tt] << 3); break; }
        }
        int m1 = (t1 < TT && mask[sb + t1] != 0.0f) ? 16 : 0;
        sxc = __builtin_amdgcn_readfirstlane(sxc);
        m1  = __builtin_amdgcn_readfirstlane(m1);
#pragma unroll 4
        for (int u = LL - 1; u >= 0; --u) {
            const int cw = __builtin_amdgcn_readfirstlane(ctrlA[wv][u]);
            if (m1) {
                const float* kp = kbase + (sxc & 7) * 68;
                const float4 k0 = *(const float4*)kp;
                const float4 k1 = *(const float4*)(kp + 4);
                const float u0 = av * ((sxc & 8) ? pL1 : pL0);
                GATHER8(u0, u1, u2, u3, u4, u5, u6, u7)
                FMASUM(acc, k0, k1, u0,u1,u2,u3,u4,u5,u6,u7)
                av = acc;
            }
            sxc = (cw & 16) ? (cw & 15) : sxc;
            m1 = cw & 16;
            if ((u & 3) == 0) {
                const float ms = gmax8(av);
                av *= __builtin_amdgcn_rcpf(ms);
                c += __logf(ms);
            }
        }
        BM[task*64 + l] = __logf(av) + c;
    }
}

// ============ Phase B: compose segment matrices (log-space LSE matvec) ============
// 1024 tasks (512 fwd seq, 512 bwd seq), 8 lanes each.
__global__ __launch_bounds__(256) void compose_kernel(
    const float* __restrict__ pi, const float* __restrict__ FM, const float* __restrict__ BM,
    float* __restrict__ SV, float* __restrict__ WV, float* __restrict__ loglik)
{
    const int tid = threadIdx.x;
    const int grp = blockIdx.x * 32 + (tid >> 3);
    const int i = tid & 7;
    if (grp < BB) {
        const int seq = grp;
        float v = __logf(pi[i]);
        for (int g = 0; g < GG; ++g) {
            SV[(seq*GG + g)*8 + i] = v;                 // incoming log-alpha state
            const float* M = FM + (size_t)(seq*GG + g) * 64;
            const float a0 = v;
            GATHER8(a0, a1, a2, a3, a4, a5, a6, a7)
            const float q0 = M[(i^0)*8 + i] + a0;
            const float q1 = M[(i^1)*8 + i] + a1;
            const float q2 = M[(i^2)*8 + i] + a2;
            const float q3 = M[(i^3)*8 + i] + a3;
            const float q4 = M[(i^4)*8 + i] + a4;
            const float q5 = M[(i^5)*8 + i] + a5;
            const float q6 = M[(i^6)*8 + i] + a6;
            const float q7 = M[(i^7)*8 + i] + a7;
            float m = fmaxf(q0, q1); m = fmaxf(m, q2); m = fmaxf(m, q3);
            m = fmaxf(m, q4); m = fmaxf(m, q5); m = fmaxf(m, q6); m = fmaxf(m, q7);
            float sum = __expf(q0-m) + __expf(q1-m) + __expf(q2-m) + __expf(q3-m)
                      + __expf(q4-m) + __expf(q5-m) + __expf(q6-m) + __expf(q7-m);
            v = m + __logf(sum);
        }
        const float gm = gmax8(v);
        const float ge = gsum8(__expf(v - gm));
        if (i == 0) loglik[seq] = gm + __logf(ge);
    } else {
        const int seq = grp - BB;
        float v = 0.0f;
        for (int g = GG - 1; g >= 0; --g) {
            WV[(seq*GG + g)*8 + i] = v;                 // incoming log-beta (raw) state
            const float* M = BM + (size_t)(seq*GG + g) * 64;
            const float a0 = v;
            GATHER8(a0, a1, a2, a3, a4, a5, a6, a7)
            const float q0 = M[(i^0)*8 + i] + a0;
            const float q1 = M[(i^1)*8 + i] + a1;
            const float q2 = M[(i^2)*8 + i] + a2;
            const float q3 = M[(i^3)*8 + i] + a3;
            const float q4 = M[(i^4)*8 + i] + a4;
            const float q5 = M[(i^5)*8 + i] + a5;
            const float q6 = M[(i^6)*8 + i] + a6;
            const float q7 = M[(i^7)*8 + i] + a7;
            float m = fmaxf(q0, q1); m = fmaxf(m, q2); m = fmaxf(m, q3);
            m = fmaxf(m, q4); m = fmaxf(m, q5); m = fmaxf(m, q6); m = fmaxf(m, q7);
            float sum = __expf(q0-m) + __expf(q1-m) + __expf(q2-m) + __expf(q3-m)
                      + __expf(q4-m) + __expf(q5-m) + __expf(q6-m) + __expf(q7-m);
            v = m + __logf(sum);
        }
    }
}

// ============ Phase C: replay segments (exact R7 step math, 8 seqs/wave) ============
// blocks [0,512) fwd, [512,1024) bwd; 4 tasks/block; task=(seqgroup, seg)
__global__ __launch_bounds__(256) void replay_kernel(
    const int* __restrict__ s, const int* __restrict__ x, const float* __restrict__ mask,
    const float* __restrict__ P, const float* __restrict__ K,
    const float* __restrict__ SV, const float* __restrict__ WV,
    float* __restrict__ alpha, float* __restrict__ betaRaw)
{
    __shared__ float kTab[5 * 68];
    __shared__ int   ctrlC[4][LL * 8];   // [slot u][g]
    const int tid = threadIdx.x;
    const int wv = tid >> 6, l = tid & 63;
    const int lo = l & 7, g = l >> 3;
    const bool isF = blockIdx.x < 512;
    const int task = (isF ? blockIdx.x : blockIdx.x - 512) * 4 + wv;
    const int sgp = task >> 5, seg = task & 31;
    const int bfirst = sgp * 8;
    const int seq = bfirst + g;
    const int sb = seq * TT;
    const int t0 = seg * LL;

    for (int e = tid; e < 340; e += 256) {
        const int ss = e / 68, idx = e - ss * 68;
        float v = 0.0f;
        if (idx < 64) {
            const int row = idx >> 3, r = idx & 7;
            v = isF ? K[ss*64 + row*8 + (row ^ r)]
                    : K[ss*64 + (row ^ r)*8 + row];
        }
        kTab[e] = v;
    }
    for (int e = l; e < LL * 8; e += 64) {
        const int slot = e >> 3, gg = e & 7;
        const int adr = (bfirst + gg) * TT + t0 + slot;
        ctrlC[wv][e] = s[adr] | (x[adr] << 3) | ((mask[adr] != 0.0f) ? 16 : 0);
    }
    __syncthreads();

    const float pL0 = P[lo*2+0], pL1 = P[lo*2+1];
    const float* kbase = kTab + lo*8;

    if (isF) {
        const float sv0 = SV[(seq*GG + seg)*8 + lo];
        const float mx = gmax8(sv0);
        float av = __expf(sv0 - mx);
        float c = mx;
        int aoff = (sb + t0) * 8 + lo;
#pragma unroll 4
        for (int u = 0; u < LL; ++u) {
            const int cw = ctrlC[wv][u*8 + g];
            const float* kp = kbase + (cw & 7) * 68;
            const float4 k0 = *(const float4*)kp;
            const float4 k1 = *(const float4*)(kp + 4);
            const float a0 = av;
            GATHER8(a0, a1, a2, a3, a4, a5, a6, a7)
            FMASUM(acc, k0, k1, a0,a1,a2,a3,a4,a5,a6,a7)
            const float nv = acc * ((cw & 8) ? pL1 : pL0);
            av = (cw & 16) ? nv : av;
            if ((u & 3) == 3) {
                const float ms = gmax8(av);
                av *= __builtin_amdgcn_rcpf(ms);
                c += __logf(ms);
            }
            alpha[aoff] = __logf(av) + c;
            aoff += 8;
        }
    } else {
        const float wv0 = WV[(seq*GG + seg)*8 + lo];
        const float mx = gmax8(wv0);
        float bv = __expf(wv0 - mx);
        float c = mx;
        const int t1 = t0 + LL;
        int m1 = 0, sxc = 0;
        if (t1 < TT) m1 = (mask[sb + t1] != 0.0f) ? 16 : 0;
        {   // per-group bounded search for first masked index >= t1
            int tt = t1;
            int found = (t1 >= TT) ? 1 : 0;
            while (!__all(found)) {
                if (!found && tt < TT) {
                    if (mask[sb + tt] != 0.0f) { sxc = s[sb+tt] | (x[sb+tt] << 3); found = 1; }
                }
                if (tt >= TT - 1) found = 1;
                ++tt;
            }
        }
        int boff = (sb + t1 - 1) * 8 + lo;
#pragma unroll 4
        for (int u = LL - 1; u >= 0; --u) {
            const int cw = ctrlC[wv][u*8 + g];
            const float* kp = kbase + (sxc & 7) * 68;
            const float4 k0 = *(const float4*)kp;
            const float4 k1 = *(const float4*)(kp + 4);
            const float u0 = bv * ((sxc & 8) ? pL1 : pL0);
            GATHER8(u0, u1, u2, u3, u4, u5, u6, u7)
            FMASUM(acc, k0, k1, u0,u1,u2,u3,u4,u5,u6,u7)
            bv = m1 ? acc : bv;
            if ((u & 3) == 0) {
                const float ms = gmax8(bv);
                bv *= __builtin_amdgcn_rcpf(ms);
                c += __logf(ms);
            }
            betaRaw[boff] = __logf(bv) + c;
            boff -= 8;
            sxc = (cw & 16) ? (cw & 15) : sxc;
            m1 = cw & 16;
        }
    }
}

// ============ beta normalize: beta[b,t,z] -= loglik[b] ============
__global__ __launch_bounds__(256) void norm_kernel(float* __restrict__ beta,
                                                   const float* __restrict__ loglik)
{
    const int i4 = blockIdx.x * 256 + threadIdx.x;      // 1,048,576 float4s
    const int b = i4 >> 11;                             // 2048 float4 per b
    const float ll = loglik[b];
    float4* p = reinterpret_cast<float4*>(beta) + i4;
    float4 v = *p;
    v.x -= ll; v.y -= ll; v.z -= ll; v.w -= ll;
    *p = v;
}

// ============ gamma + xi: streaming, 4 t-rows per wave, float4 xi stores ============
// (normalizations are exact no-ops by the forward-backward invariant)
__global__ __launch_bounds__(256) void post_kernel(
    const int* __restrict__ s, const int* __restrict__ x, const float* __restrict__ mask,
    const float* __restrict__ P, const float* __restrict__ K,
    const float* __restrict__ alpha, const float* __restrict__ beta,
    float* __restrict__ gamma, float* __restrict__ xi)
{
    __shared__ float lK[320];
    __shared__ float lP0[8], lP1[8];
    const int tid = threadIdx.x;
    for (int e = tid; e < 320; e += 256) lK[e] = __logf(K[e]);
    if (tid < 8) { lP0[tid] = __logf(P[tid*2]); lP1[tid] = __logf(P[tid*2+1]); }
    __syncthreads();

    const int w = blockIdx.x * 4 + (tid >> 6);    // wave id, [0, BB*TT/4)
    const int l = tid & 63;
    const int b = w >> 8;                          // 256 waves per b
    const int t0 = (w & 255) * 4;
    const long bt0 = (long)b * TT + t0;

    // gamma: lanes 0..31 cover 4 rows x 8 states
    if (l < 32) {
        const int qg = l >> 3, z = l & 7;
        const long bt = bt0 + qg;
        const float m0 = mask[bt];
        const float a = alpha[bt*8 + z];
        const float bb = beta[bt*8 + z];
        gamma[bt*8 + z] = (m0 != 0.0f) ? (a + bb) : NINF;
    }
    // xi: row q = l>>4, 16 lanes x float4 per row
    const int q = l >> 4, ll = l & 15;
    const long t = t0 + q;
    const long bt = bt0 + q;
    const bool wx = (t < TT - 1);
    const long tn = wx ? (bt + 1) : bt;            // safe address
    const float m1 = mask[tn];
    const int svv = s[bt];
    const int xv = x[tn];
    const int i = ll >> 1;
    const int bj = (ll & 1) * 4;
    float4 out;
    if (wx && m1 != 0.0f) {
        const float aHi = alpha[bt*8 + i];
        const float4 bN = *(const float4*)&beta[tn*8 + bj];
        const float4 kv = *(const float4*)&lK[svv*64 + ll*4];
        const float4 p0 = *(const float4*)&lP0[bj];
        const float4 p1 = *(const float4*)&lP1[bj];
        out.x = kv.x + aHi + bN.x + (xv ? p1.x : p0.x);
        out.y = kv.y + aHi + bN.y + (xv ? p1.y : p0.y);
        out.z = kv.z + aHi + bN.z + (xv ? p1.z : p0.z);
        out.w = kv.w + aHi + bN.w + (xv ? p1.w : p0.w);
    } else {
        out.x = NINF; out.y = NINF; out.z = NINF; out.w = NINF;
    }
    if (wx) *(float4*)&xi[((long)b*(TT-1) + t)*64 + ll*4] = out;
}

extern "C" void kernel_launch(void* const* d_in, const int* in_sizes, int n_in,
                              void* d_out, int out_size, void* d_ws, size_t ws_size,
                              hipStream_t stream) {
    const int*   s    = (const int*)d_in[0];
    const int*   x    = (const int*)d_in[1];
    const float* mask = (const float*)d_in[2];
    const float* pi   = (const float*)d_in[3];
    const float* P    = (const float*)d_in[4];
    const float* K    = (const float*)d_in[5];

    float* out    = (float*)d_out;
    float* gamma  = out;                                  // (B,T,Z)
    float* xi     = gamma + (size_t)BB * TT * 8;          // (B,T-1,Z,Z) = 33,521,664 floats
    float* alpha  = xi + (size_t)BB * (TT - 1) * 64;      // (B,T,Z)
    float* beta   = alpha + (size_t)BB * TT * 8;          // (B,T,Z)
    float* loglik = beta + (size_t)BB * TT * 8;           // (B,)

    // scratch inside xi tail (post overwrites xi only after replay):
    // 31,000,000 + 2*1,048,576 + 2*131,072 = 33,359,296 <= 33,521,664
    float* FMs = xi + (size_t)31000000;
    float* BMs = FMs + (size_t)BB * GG * 64;
    float* SVs = BMs + (size_t)BB * GG * 64;
    float* WVs = SVs + (size_t)BB * GG * 8;

    segmat_kernel<<<8192, 256, 0, stream>>>(s, x, mask, P, K, FMs, BMs);
    compose_kernel<<<32, 256, 0, stream>>>(pi, FMs, BMs, SVs, WVs, loglik);
    replay_kernel<<<1024, 256, 0, stream>>>(s, x, mask, P, K, SVs, WVs, alpha, beta);
    norm_kernel<<<4096, 256, 0, stream>>>(beta, loglik);
    post_kernel<<<BB * TT / 16, 256, 0, stream>>>(s, x, mask, P, K, alpha, beta, gamma, xi);
}